// Round 19
// baseline (432.499 us; speedup 1.0000x reference)
//
#include <hip/hip_runtime.h>
#include <hip/hip_bf16.h>
#include <cstdint>
#include <cstddef>

#define B_ 4
#define S_ 1024
#define V_ 32000
#define D_ 256
#define H_ 8
#define DH_ 32
#define L_ 4
#define MROWS (B_*S_)

typedef __attribute__((ext_vector_type(8))) short bf16x8;
typedef __attribute__((ext_vector_type(4))) float f32x4;

__device__ __forceinline__ unsigned short f2bf(float f) {
  union { float f; unsigned u; } c; c.f = f;
  unsigned u = c.u;
  u += 0x7fff + ((u >> 16) & 1);   // round-to-nearest-even
  return (unsigned short)(u >> 16);
}
__device__ __forceinline__ float bf2f(unsigned short u) {
  union { unsigned u; float f; } c; c.u = ((unsigned)u) << 16; return c.f;
}

// async global->LDS, 16B per lane; LDS dest is wave-uniform base + lane*16
__device__ __forceinline__ void gload16(const unsigned short* g, unsigned short* l) {
  __builtin_amdgcn_global_load_lds(
      (const __attribute__((address_space(1))) void*)g,
      (__attribute__((address_space(3))) void*)l, 16, 0, 0);
}

// ---- XOR-swizzled LDS tiles: lds[row][inner ^ ((row&7)<<4)] = g[row][inner]
template<int BM, int BK, int NW>
__device__ __forceinline__ void stage_tile_swz(const unsigned short* __restrict__ g, int ldg,
                                               unsigned short* lds, int wave, int lane) {
  constexpr int CH  = BM * BK * 2 / 1024;   // 1KB chunks
  constexpr int BKB = BK * 2;               // bytes per row
#pragma unroll
  for (int t = 0; t < CH / NW; ++t) {
    int c = wave + t * NW;
    int byte  = c * 1024 + lane * 16;
    int row   = byte / BKB;
    int inner = (byte % BKB) ^ ((row & 7) << 4);
    gload16(g + (size_t)row * ldg + (inner >> 1), lds + c * 512);
  }
}

// swizzled 16B fragment read: row-major [*][BKB/2] tile, kbytes multiple of 16
template<int BKB>
__device__ __forceinline__ bf16x8 lds_frag(const unsigned short* base, int row, int kbytes) {
  int b = (row * BKB + kbytes) ^ ((row & 7) << 4);
  return *(const bf16x8*)((const char*)base + b);
}

// ---------------- embed + LN(layer0) + dual-layout emit ----------------
__global__ __launch_bounds__(512) void k_embln(
    const int* __restrict__ X, const float* __restrict__ emb,
    const float* __restrict__ lng, const float* __restrict__ lnb,
    float* __restrict__ x, unsigned short* __restrict__ xbf,
    unsigned short* __restrict__ xnT) {
  __shared__ __align__(16) float xf[16][264];
  __shared__ float mrow[16], rrow[16];
  int r0 = blockIdx.x * 16;
  int tid = threadIdx.x;
  int w = tid >> 6, lane = tid & 63;
#pragma unroll
  for (int rr = 0; rr < 2; rr++) {
    int row = w * 2 + rr; int grow = r0 + row;
    int tok = X[grow];
    f32x4 v = *(const f32x4*)(emb + (size_t)tok * D_ + lane * 4);
    *(f32x4*)(x + (size_t)grow * D_ + lane * 4) = v;
    *(f32x4*)&xf[row][lane * 4] = v;
    float s = v[0] + v[1] + v[2] + v[3];
    float ss = v[0]*v[0] + v[1]*v[1] + v[2]*v[2] + v[3]*v[3];
#pragma unroll
    for (int off = 1; off < 64; off <<= 1) {
      s  += __shfl_xor(s, off, 64);
      ss += __shfl_xor(ss, off, 64);
    }
    float mean = s * (1.f / D_);
    float var = ss * (1.f / D_) - mean * mean;
    float rinv = rsqrtf(var + 1e-5f);
    float4 g4 = *(const float4*)(lng + lane * 4);
    float4 b4 = *(const float4*)(lnb + lane * 4);
    ushort4 o;
    o.x = f2bf((v[0] - mean) * rinv * g4.x + b4.x);
    o.y = f2bf((v[1] - mean) * rinv * g4.y + b4.y);
    o.z = f2bf((v[2] - mean) * rinv * g4.z + b4.z);
    o.w = f2bf((v[3] - mean) * rinv * g4.w + b4.w);
    *(ushort4*)(xbf + (size_t)grow * D_ + lane * 4) = o;
    if (lane == 0) { mrow[row] = mean; rrow[row] = rinv; }
  }
  __syncthreads();
  int d = tid & 255, half = tid >> 8;
  float gd = lng[d], bd = lnb[d];
  int bb = r0 >> 10, s0 = r0 & 1023;
  bf16x8 o8;
#pragma unroll
  for (int k = 0; k < 8; k++) {
    int srow = half * 8 + k;
    o8[k] = (short)f2bf((xf[srow][d] - mrow[srow]) * rrow[srow] * gd + bd);
  }
  *(bf16x8*)(xnT + ((size_t)(bb * 256 + d)) * S_ + s0 + half * 8) = o8;
}

// ---------------- fused layer (round-13 best): attn + 3-GEMM MLP -----------------
template<int LAST>
__global__ __launch_bounds__(512) void k_layer(
    const unsigned short* __restrict__ xbf,   // layer input  [4096][256] bf16
    const unsigned short* __restrict__ xnT,   // layer input  [4][256][1024] bf16
    const float* __restrict__ WQ, const float* __restrict__ WK,
    const float* __restrict__ WV, const float* __restrict__ Om,
    const unsigned short* __restrict__ Wl,    // 3 x [256][256] bf16 (this layer)
    const float* __restrict__ b1, const float* __restrict__ b2, const float* __restrict__ b3,
    float* __restrict__ x,                    // residual f32
    const float* __restrict__ lngN, const float* __restrict__ lnbN,
    unsigned short* __restrict__ xbfN, unsigned short* __restrict__ xnTN,  // outputs (!LAST)
    unsigned short* __restrict__ actB,        // output (LAST)
    int layer) {
  __shared__ __align__(16) unsigned short P_lds[8][16][72];
  __shared__ __align__(16) unsigned short Aa[16 * 256];
  __shared__ __align__(16) unsigned short Ab[16 * 256];
  __shared__ __align__(16) unsigned short Ab2[16 * 256];
  __shared__ __align__(16) unsigned short Bp[2][256 * 64];
  __shared__ __align__(16) float xf[16][264];
  __shared__ float mrow[16], rrow[16];

  int b = blockIdx.x >> 6;
  int q0 = (blockIdx.x & 63) << 4;
  int r0 = blockIdx.x * 16;                  // == b*S + q0
  int tid = threadIdx.x;
  int w = tid >> 6, lane = tid & 63;
  int lr = lane & 15, lg = lane >> 4;
  int h = w;

  // prefetch MLP W panel 0 (drained at the post-attention barrier)
  stage_tile_swz<256, 64, 8>(Wl, 256, Bp[0], w, lane);

  // ================= attention =================
  const float scale = 0.17677669529663687f;  // 1/sqrt(32)
  bf16x8 aq;
  {
    bf16x8 xq = *(const bf16x8*)(xbf + ((size_t)(b * S_ + q0 + lr)) * D_ + h * DH_ + lg * 8);
#pragma unroll
    for (int j = 0; j < 8; j++) {
      int dj = lg * 8 + j;
      float wq = WQ[((size_t)(layer * H_ + h)) * 1024 + dj * 33];
      float wk = WK[((size_t)(layer * H_ + h)) * 1024 + dj * 33];
      aq[j] = (short)f2bf(bf2f((unsigned short)xq[j]) * wq * wk * scale);
    }
  }
  float dvo[2];
#pragma unroll
  for (int fs = 0; fs < 2; fs++) {
    int fh = fs * 16 + lr;
    int fc = h * DH_ + fh;
    dvo[fs] = WV[((size_t)(layer * H_ + h)) * 1024 + fh * 33] *
              Om[(size_t)layer * 65536 + (size_t)fc * 257];
  }

  f32x4 accPV[2];
  accPV[0] = (f32x4){0.f, 0.f, 0.f, 0.f};
  accPV[1] = (f32x4){0.f, 0.f, 0.f, 0.f};
  float rsum[4] = {0.f, 0.f, 0.f, 0.f};

  const unsigned short* xk_base = xbf + ((size_t)b * S_) * D_ + h * DH_ + lg * 8;
  const unsigned short* vT_base = xnT + ((size_t)(b * D_ + h * DH_)) * S_;

  bf16x8 qkb[4];
#pragma unroll
  for (int c = 0; c < 4; c++)
    qkb[c] = *(const bf16x8*)(xk_base + (size_t)(c * 16 + lr) * D_);

  for (int kt = 0; kt < 16; kt++) {
    int k0 = kt * 64;
    bf16x8 pvb[2][2];
#pragma unroll
    for (int fs = 0; fs < 2; fs++)
#pragma unroll
      for (int kc = 0; kc < 2; kc++)
        pvb[fs][kc] = *(const bf16x8*)(vT_base + (size_t)(fs * 16 + lr) * S_ +
                                       k0 + kc * 32 + lg * 8);
    f32x4 s[4];
#pragma unroll
    for (int c = 0; c < 4; c++)
      s[c] = __builtin_amdgcn_mfma_f32_16x16x32_bf16(aq, qkb[c],
                (f32x4){0.f, 0.f, 0.f, 0.f}, 0, 0, 0);
    int ktn = kt < 15 ? kt + 1 : 15;
#pragma unroll
    for (int c = 0; c < 4; c++)
      qkb[c] = *(const bf16x8*)(xk_base + (size_t)(ktn * 64 + c * 16 + lr) * D_);
#pragma unroll
    for (int c = 0; c < 4; c++)
#pragma unroll
      for (int r = 0; r < 4; r++) {
        float p = __expf(s[c][r]);
        rsum[r] += p;
        P_lds[w][lg * 4 + r][c * 16 + lr] = f2bf(p);
      }
#pragma unroll
    for (int kc = 0; kc < 2; kc++) {
      bf16x8 pa = *(const bf16x8*)(&P_lds[w][lr][kc * 32 + lg * 8]);
#pragma unroll
      for (int fs = 0; fs < 2; fs++)
        accPV[fs] = __builtin_amdgcn_mfma_f32_16x16x32_bf16(pa, pvb[fs][kc],
                       accPV[fs], 0, 0, 0);
    }
  }

  float inv[4];
#pragma unroll
  for (int r = 0; r < 4; r++) {
    float v = rsum[r];
    v += __shfl_xor(v, 1, 64);
    v += __shfl_xor(v, 2, 64);
    v += __shfl_xor(v, 4, 64);
    v += __shfl_xor(v, 8, 64);
    inv[r] = 1.f / v;
  }
  // attention out -> LDS Aa (swizzled [16][256], BKB=512)
#pragma unroll
  for (int fs = 0; fs < 2; fs++)
#pragma unroll
    for (int r = 0; r < 4; r++) {
      float val = accPV[fs][r] * inv[r] * dvo[fs];
      int row = lg * 4 + r, col = h * DH_ + fs * 16 + lr;
      int byte = (row * 512 + col * 2) ^ ((row & 7) << 4);
      *(unsigned short*)((char*)Aa + byte) = f2bf(val);
    }
  __syncthreads();   // Aa visible to all waves; W panel 0 drained

  // ================= MLP: 12 panels (3 gemms x 4 k-steps), prefetch pipeline ====
  int lr16 = lr;
  f32x4 acc[2];
  acc[0] = (f32x4){0.f, 0.f, 0.f, 0.f};
  acc[1] = (f32x4){0.f, 0.f, 0.f, 0.f};
  const unsigned short* Asrc = Aa;

  for (int p = 0; p < 12; ++p) {
    if (p < 11) {
      int pn = p + 1;
      stage_tile_swz<256, 64, 8>(Wl + (size_t)(pn >> 2) * 65536 + (pn & 3) * 64,
                                 256, Bp[pn & 1], w, lane);
    }
    int kk0 = (p & 3) * 64;
#pragma unroll
    for (int kk = 0; kk < 64; kk += 32) {
      bf16x8 a = lds_frag<512>(Asrc, lr16, (kk0 + kk) * 2 + lg * 16);
#pragma unroll
      for (int j = 0; j < 2; j++) {
        bf16x8 bfg = lds_frag<128>(Bp[p & 1], w * 32 + j * 16 + lr16, kk * 2 + lg * 16);
        acc[j] = __builtin_amdgcn_mfma_f32_16x16x32_bf16(a, bfg, acc[j], 0, 0, 0);
      }
    }
    if (p == 3 || p == 7) {
      const float* bias = (p == 3) ? b1 : b2;
      unsigned short* dst = (p == 3) ? Ab : Ab2;
#pragma unroll
      for (int j = 0; j < 2; j++) {
        int col = w * 32 + j * 16 + lr16;
        float bv = bias[col];
#pragma unroll
        for (int r = 0; r < 4; r++) {
          float v = acc[j][r] + bv;
          v = 0.5f * v * (1.f + erff(v * 0.70710678118654752f));
          int row = lg * 4 + r;
          int byte = (row * 512 + col * 2) ^ ((row & 7) << 4);
          *(unsigned short*)((char*)dst + byte) = f2bf(v);
        }
      }
      acc[0] = (f32x4){0.f, 0.f, 0.f, 0.f};
      acc[1] = (f32x4){0.f, 0.f, 0.f, 0.f};
      Asrc = (p == 3) ? Ab : Ab2;
    }
    __syncthreads();
  }

  // ---- final epilogue: bias3 + residual (+ next-layer LN dual emit) ----
#pragma unroll
  for (int j = 0; j < 2; j++) {
    int col = w * 32 + j * 16 + lr16;
    float bv = b3[col];
#pragma unroll
    for (int r = 0; r < 4; r++) {
      int row = lg * 4 + r; int grow = r0 + row;
      float v = acc[j][r] + bv + x[(size_t)grow * D_ + col];
      if constexpr (LAST) {
        actB[(size_t)grow * D_ + col] = f2bf(v);
      } else {
        x[(size_t)grow * D_ + col] = v;
        xf[row][col] = v;
      }
    }
  }

  if constexpr (!LAST) {
    __syncthreads();
#pragma unroll
    for (int rr = 0; rr < 2; rr++) {
      int row = w * 2 + rr; int grow = r0 + row;
      f32x4 v = *(const f32x4*)&xf[row][lane * 4];
      float s = v[0] + v[1] + v[2] + v[3];
      float ss = v[0]*v[0] + v[1]*v[1] + v[2]*v[2] + v[3]*v[3];
#pragma unroll
      for (int off = 1; off < 64; off <<= 1) {
        s  += __shfl_xor(s, off, 64);
        ss += __shfl_xor(ss, off, 64);
      }
      float mean = s * (1.f / D_);
      float var = ss * (1.f / D_) - mean * mean;
      float rinv = rsqrtf(var + 1e-5f);
      float4 g4 = *(const float4*)(lngN + lane * 4);
      float4 b4 = *(const float4*)(lnbN + lane * 4);
      ushort4 o;
      o.x = f2bf((v[0] - mean) * rinv * g4.x + b4.x);
      o.y = f2bf((v[1] - mean) * rinv * g4.y + b4.y);
      o.z = f2bf((v[2] - mean) * rinv * g4.z + b4.z);
      o.w = f2bf((v[3] - mean) * rinv * g4.w + b4.w);
      *(ushort4*)(xbfN + (size_t)grow * D_ + lane * 4) = o;
      if (lane == 0) { mrow[row] = mean; rrow[row] = rinv; }
    }
    __syncthreads();
    int d = tid & 255, half = tid >> 8;
    float gd = lngN[d], bd = lnbN[d];
    int bb = r0 >> 10, s0 = r0 & 1023;
    bf16x8 o8;
#pragma unroll
    for (int k = 0; k < 8; k++) {
      int srow = half * 8 + k;
      o8[k] = (short)f2bf((xf[srow][d] - mrow[srow]) * rrow[srow] * gd + bd);
    }
    *(bf16x8*)(xnTN + ((size_t)(bb * 256 + d)) * S_ + s0 + half * 8) = o8;
  }
}

// ---------------- logits GEMM v6: barrier-free, A direct from L2 ----------------
// 250 blocks x 512 thr. B transposed+converted once into 64KB LDS, hoisted to
// registers (Bs then dead). t-loop has ZERO barriers and ZERO LDS traffic: each
// wave reads its A fragments straight from global (A = 2MB, L2-resident on every
// XCD) and nt-stores its C tile. 8 independent waves/block hide L2 latency.
__global__ __launch_bounds__(512) void k_logits(
    const unsigned short* __restrict__ A,    // bf16 [4096][256]
    const float* __restrict__ logitW,        // f32 [256][32000]
    float* __restrict__ C) {
  __shared__ __align__(16) unsigned short Bs[128 * 256];    // 64 KB (init only)

  int tid = threadIdx.x, lane = tid & 63, w = tid >> 6;
  int wm = w >> 2, wn = w & 3;               // 2 (row-groups) x 4 (col-groups)
  int lr = lane & 15, lg = lane >> 4;
  int bn0 = blockIdx.x * 128;

  // B-stage: transpose + convert logitW -> Bs [row=v][k] bf16, swizzled (BKB=512)
  {
    int c = tid & 127;          // col within slab (v - bn0)
    int kp = tid >> 7;          // 0..3
    for (int it = 0; it < 32; ++it) {
      int k = it * 8 + kp * 2;
      float f0 = logitW[(size_t)k * V_ + bn0 + c];
      float f1 = logitW[(size_t)(k + 1) * V_ + bn0 + c];
      unsigned pack = (unsigned)f2bf(f0) | ((unsigned)f2bf(f1) << 16);
      int byte = (c * 512 + k * 2) ^ ((c & 7) << 4);
      *(unsigned*)((char*)Bs + byte) = pack;
    }
  }
  __syncthreads();

  // hoist B fragments to registers (Bs dead afterwards)
  bf16x8 breg[2][8];
#pragma unroll
  for (int j = 0; j < 2; j++)
#pragma unroll
    for (int ks = 0; ks < 8; ks++)
      breg[j][ks] = lds_frag<512>(Bs, wn * 32 + j * 16 + lr, ks * 64 + lg * 16);

  // per-wave A row base: rows wm*32 + i*16 + lr, k-offset ks*32 + lg*8 elements
  const unsigned short* Arow0 = A + (size_t)(wm * 32 + lr) * 256 + lg * 8;
  const unsigned short* Arow1 = Arow0 + 16 * 256;

  for (int t = 0; t < 64; ++t) {
    const unsigned short* At0 = Arow0 + (size_t)t * 64 * 256;
    const unsigned short* At1 = Arow1 + (size_t)t * 64 * 256;

    f32x4 acc[2][2];
#pragma unroll
    for (int i = 0; i < 2; i++)
#pragma unroll
      for (int j = 0; j < 2; j++) acc[i][j] = (f32x4){0.f, 0.f, 0.f, 0.f};

#pragma unroll
    for (int ks = 0; ks < 8; ks++) {
      bf16x8 af0 = *(const bf16x8*)(At0 + ks * 32);
      bf16x8 af1 = *(const bf16x8*)(At1 + ks * 32);
      // swapped operands: lane = A-row (lr), regs = 4 vocab cols
#pragma unroll
      for (int j = 0; j < 2; j++) {
        acc[0][j] = __builtin_amdgcn_mfma_f32_16x16x32_bf16(breg[j][ks], af0, acc[0][j], 0, 0, 0);
        acc[1][j] = __builtin_amdgcn_mfma_f32_16x16x32_bf16(breg[j][ks], af1, acc[1][j], 0, 0, 0);
      }
    }

    int r0 = t * 64;
#pragma unroll
    for (int i = 0; i < 2; i++)
#pragma unroll
      for (int j = 0; j < 2; j++) {
        int row = r0 + wm * 32 + i * 16 + lr;
        int colb = bn0 + wn * 32 + j * 16 + lg * 4;
        __builtin_nontemporal_store(acc[i][j], (f32x4*)(C + (size_t)row * V_ + colb));
      }
  }
}

// ---------------- transpose + f32->bf16 convert (MLP weights) ----------------
__device__ __forceinline__ void tconv_tile(const float* __restrict__ in,
                                           unsigned short* __restrict__ out,
                                           int R, int C, int r0, int c0, int t) {
  __shared__ float tile[64][65];
#pragma unroll
  for (int i = 0; i < 16; i++) {
    int idx = i * 256 + t;
    int lr = idx >> 6, lc = idx & 63;
    tile[lr][lc] = in[(size_t)(r0 + lr) * C + c0 + lc];
  }
  __syncthreads();
#pragma unroll
  for (int i = 0; i < 16; i++) {
    int idx = i * 256 + t;
    int lr = idx >> 6, lc = idx & 63;
    out[(size_t)(c0 + lr) * R + r0 + lc] = f2bf(tile[lc][lr]);
  }
}

__global__ __launch_bounds__(256) void k_tconv_mlp(const float* __restrict__ w1,
                                                   const float* __restrict__ w2,
                                                   const float* __restrict__ w3,
                                                   unsigned short* __restrict__ out) {
  int z = blockIdx.z; int l = z / 3, mm = z % 3;
  const float* in = (mm == 0 ? w1 : mm == 1 ? w2 : w3) + (size_t)l * 65536;
  tconv_tile(in, out + (size_t)z * 65536, 256, 256, blockIdx.y * 64, blockIdx.x * 64, threadIdx.x);
}

// ---------------- launch ----------------
extern "C" void kernel_launch(void* const* d_in, const int* in_sizes, int n_in,
                              void* d_out, int out_size, void* d_ws, size_t ws_size,
                              hipStream_t stream) {
  const int*   X      = (const int*)d_in[0];
  const float* emb    = (const float*)d_in[1];
  const float* WQ     = (const float*)d_in[2];
  const float* WK     = (const float*)d_in[3];
  const float* WV     = (const float*)d_in[4];
  const float* Om     = (const float*)d_in[5];
  const float* lng    = (const float*)d_in[6];
  const float* lnb    = (const float*)d_in[7];
  const float* w1     = (const float*)d_in[8];
  const float* b1     = (const float*)d_in[9];
  const float* w2     = (const float*)d_in[10];
  const float* b2     = (const float*)d_in[11];
  const float* w3     = (const float*)d_in[12];
  const float* b3     = (const float*)d_in[13];
  const float* logitW = (const float*)d_in[14];
  float* out = (float*)d_out;
  char* ws = (char*)d_ws;

  constexpr size_t MB = 1024u * 1024;
  float* x  = (float*)(ws);                                    // 4 MB
  unsigned short* xbf0 = (unsigned short*)(ws + 4 * MB);       // 2 MB
  unsigned short* xbf1 = (unsigned short*)(ws + 6 * MB);       // 2 MB
  unsigned short* xnT0 = (unsigned short*)(ws + 8 * MB);       // 2 MB
  unsigned short* xnT1 = (unsigned short*)(ws + 10 * MB);      // 2 MB
  unsigned short* actB = (unsigned short*)(ws + 12 * MB);      // 2 MB
  unsigned short* mlpW = (unsigned short*)(ws + 14 * MB);      // 1.5 MB

  // MLP weight conversion only (logits W transposed in-kernel)
  k_tconv_mlp<<<dim3(4, 4, 12), 256, 0, stream>>>(w1, w2, w3, mlpW);

  k_embln<<<256, 512, 0, stream>>>(X, emb, lng, lnb, x, xbf0, xnT0);

  for (int l = 0; l < L_; l++) {
    const unsigned short* xbfI = (l & 1) ? xbf1 : xbf0;
    const unsigned short* xnTI = (l & 1) ? xnT1 : xnT0;
    unsigned short* xbfO = (l & 1) ? xbf0 : xbf1;
    unsigned short* xnTO = (l & 1) ? xnT0 : xnT1;
    if (l < L_ - 1) {
      k_layer<0><<<256, 512, 0, stream>>>(
          xbfI, xnTI, WQ, WK, WV, Om, mlpW + (size_t)(l * 3) * 65536,
          b1 + (size_t)l * D_, b2 + (size_t)l * D_, b3 + (size_t)l * D_, x,
          lng + (size_t)(l + 1) * D_, lnb + (size_t)(l + 1) * D_,
          xbfO, xnTO, nullptr, l);
    } else {
      k_layer<1><<<256, 512, 0, stream>>>(
          xbfI, xnTI, WQ, WK, WV, Om, mlpW + (size_t)(l * 3) * 65536,
          b1 + (size_t)l * D_, b2 + (size_t)l * D_, b3 + (size_t)l * D_, x,
          nullptr, nullptr, nullptr, nullptr, actB, l);
    }
  }

  // logits: barrier-free, A-from-L2, nt stores
  k_logits<<<250, 512, 0, stream>>>(actB, logitW, out);
}

// Round 20
// 328.788 us; speedup vs baseline: 1.3154x; 1.3154x over previous
//
#include <hip/hip_runtime.h>
#include <hip/hip_bf16.h>
#include <cstdint>
#include <cstddef>

#define B_ 4
#define S_ 1024
#define V_ 32000
#define D_ 256
#define H_ 8
#define DH_ 32
#define L_ 4
#define MROWS (B_*S_)

typedef __attribute__((ext_vector_type(8))) short bf16x8;
typedef __attribute__((ext_vector_type(4))) float f32x4;

__device__ __forceinline__ unsigned short f2bf(float f) {
  union { float f; unsigned u; } c; c.f = f;
  unsigned u = c.u;
  u += 0x7fff + ((u >> 16) & 1);   // round-to-nearest-even
  return (unsigned short)(u >> 16);
}
__device__ __forceinline__ float bf2f(unsigned short u) {
  union { unsigned u; float f; } c; c.u = ((unsigned)u) << 16; return c.f;
}

// async global->LDS, 16B per lane; LDS dest is wave-uniform base + lane*16
__device__ __forceinline__ void gload16(const unsigned short* g, unsigned short* l) {
  __builtin_amdgcn_global_load_lds(
      (const __attribute__((address_space(1))) void*)g,
      (__attribute__((address_space(3))) void*)l, 16, 0, 0);
}

// ---- XOR-swizzled LDS tiles: lds[row][inner ^ ((row&7)<<4)] = g[row][inner]
template<int BM, int BK, int NW>
__device__ __forceinline__ void stage_tile_swz(const unsigned short* __restrict__ g, int ldg,
                                               unsigned short* lds, int wave, int lane) {
  constexpr int CH  = BM * BK * 2 / 1024;   // 1KB chunks
  constexpr int BKB = BK * 2;               // bytes per row
#pragma unroll
  for (int t = 0; t < CH / NW; ++t) {
    int c = wave + t * NW;
    int byte  = c * 1024 + lane * 16;
    int row   = byte / BKB;
    int inner = (byte % BKB) ^ ((row & 7) << 4);
    gload16(g + (size_t)row * ldg + (inner >> 1), lds + c * 512);
  }
}

// swizzled 16B fragment read: row-major [*][BKB/2] tile, kbytes multiple of 16
template<int BKB>
__device__ __forceinline__ bf16x8 lds_frag(const unsigned short* base, int row, int kbytes) {
  int b = (row * BKB + kbytes) ^ ((row & 7) << 4);
  return *(const bf16x8*)((const char*)base + b);
}

// ---------------- fused prep: embln (blocks 0..255) + MLP W tconv (256..447) ------
// The two halves touch disjoint data; fusing removes one dispatch drain.
__global__ __launch_bounds__(512) void k_prep(
    const int* __restrict__ X, const float* __restrict__ emb,
    const float* __restrict__ lng, const float* __restrict__ lnb,
    float* __restrict__ x, unsigned short* __restrict__ xbf,
    unsigned short* __restrict__ xnT,
    const float* __restrict__ w1, const float* __restrict__ w2,
    const float* __restrict__ w3, unsigned short* __restrict__ mlpW) {
  int tid = threadIdx.x;
  if (blockIdx.x < 256) {
    // ---- embln ----
    __shared__ __align__(16) float xf[16][264];
    __shared__ float mrow[16], rrow[16];
    int r0 = blockIdx.x * 16;
    int w = tid >> 6, lane = tid & 63;
#pragma unroll
    for (int rr = 0; rr < 2; rr++) {
      int row = w * 2 + rr; int grow = r0 + row;
      int tok = X[grow];
      f32x4 v = *(const f32x4*)(emb + (size_t)tok * D_ + lane * 4);
      *(f32x4*)(x + (size_t)grow * D_ + lane * 4) = v;
      *(f32x4*)&xf[row][lane * 4] = v;
      float s = v[0] + v[1] + v[2] + v[3];
      float ss = v[0]*v[0] + v[1]*v[1] + v[2]*v[2] + v[3]*v[3];
#pragma unroll
      for (int off = 1; off < 64; off <<= 1) {
        s  += __shfl_xor(s, off, 64);
        ss += __shfl_xor(ss, off, 64);
      }
      float mean = s * (1.f / D_);
      float var = ss * (1.f / D_) - mean * mean;
      float rinv = rsqrtf(var + 1e-5f);
      float4 g4 = *(const float4*)(lng + lane * 4);
      float4 b4 = *(const float4*)(lnb + lane * 4);
      ushort4 o;
      o.x = f2bf((v[0] - mean) * rinv * g4.x + b4.x);
      o.y = f2bf((v[1] - mean) * rinv * g4.y + b4.y);
      o.z = f2bf((v[2] - mean) * rinv * g4.z + b4.z);
      o.w = f2bf((v[3] - mean) * rinv * g4.w + b4.w);
      *(ushort4*)(xbf + (size_t)grow * D_ + lane * 4) = o;
      if (lane == 0) { mrow[row] = mean; rrow[row] = rinv; }
    }
    __syncthreads();
    int d = tid & 255, half = tid >> 8;
    float gd = lng[d], bd = lnb[d];
    int bb = r0 >> 10, s0 = r0 & 1023;
    bf16x8 o8;
#pragma unroll
    for (int k = 0; k < 8; k++) {
      int srow = half * 8 + k;
      o8[k] = (short)f2bf((xf[srow][d] - mrow[srow]) * rrow[srow] * gd + bd);
    }
    *(bf16x8*)(xnT + ((size_t)(bb * 256 + d)) * S_ + s0 + half * 8) = o8;
  } else {
    // ---- MLP weight transpose+convert (192 logical blocks, 256 active threads) ----
    __shared__ float tile[64][65];
    int idx = blockIdx.x - 256;               // 0..191
    int z = idx >> 4;                         // 0..11  (l*3+mm)
    int rem = idx & 15;
    int r0 = (rem >> 2) * 64, c0 = (rem & 3) * 64;
    int l = z / 3, mm = z % 3;
    const float* in = (mm == 0 ? w1 : mm == 1 ? w2 : w3) + (size_t)l * 65536;
    unsigned short* out = mlpW + (size_t)z * 65536;
    int t = tid & 255;
    bool act = tid < 256;
    if (act) {
#pragma unroll
      for (int i = 0; i < 16; i++) {
        int id2 = i * 256 + t;
        int lr = id2 >> 6, lc = id2 & 63;
        tile[lr][lc] = in[(size_t)(r0 + lr) * 256 + c0 + lc];
      }
    }
    __syncthreads();
    if (act) {
#pragma unroll
      for (int i = 0; i < 16; i++) {
        int id2 = i * 256 + t;
        int lr = id2 >> 6, lc = id2 & 63;
        out[(size_t)(c0 + lr) * 256 + r0 + lc] = f2bf(tile[lc][lr]);
      }
    }
  }
}

// ---------------- fused layer (round-13 best): attn + 3-GEMM MLP -----------------
template<int LAST>
__global__ __launch_bounds__(512) void k_layer(
    const unsigned short* __restrict__ xbf,   // layer input  [4096][256] bf16
    const unsigned short* __restrict__ xnT,   // layer input  [4][256][1024] bf16
    const float* __restrict__ WQ, const float* __restrict__ WK,
    const float* __restrict__ WV, const float* __restrict__ Om,
    const unsigned short* __restrict__ Wl,    // 3 x [256][256] bf16 (this layer)
    const float* __restrict__ b1, const float* __restrict__ b2, const float* __restrict__ b3,
    float* __restrict__ x,                    // residual f32
    const float* __restrict__ lngN, const float* __restrict__ lnbN,
    unsigned short* __restrict__ xbfN, unsigned short* __restrict__ xnTN,  // outputs (!LAST)
    unsigned short* __restrict__ actB,        // output (LAST)
    int layer) {
  __shared__ __align__(16) unsigned short P_lds[8][16][72];
  __shared__ __align__(16) unsigned short Aa[16 * 256];
  __shared__ __align__(16) unsigned short Ab[16 * 256];
  __shared__ __align__(16) unsigned short Ab2[16 * 256];
  __shared__ __align__(16) unsigned short Bp[2][256 * 64];
  __shared__ __align__(16) float xf[16][264];
  __shared__ float mrow[16], rrow[16];

  int b = blockIdx.x >> 6;
  int q0 = (blockIdx.x & 63) << 4;
  int r0 = blockIdx.x * 16;                  // == b*S + q0
  int tid = threadIdx.x;
  int w = tid >> 6, lane = tid & 63;
  int lr = lane & 15, lg = lane >> 4;
  int h = w;

  // prefetch MLP W panel 0 (drained at the post-attention barrier)
  stage_tile_swz<256, 64, 8>(Wl, 256, Bp[0], w, lane);

  // ================= attention =================
  const float scale = 0.17677669529663687f;  // 1/sqrt(32)
  bf16x8 aq;
  {
    bf16x8 xq = *(const bf16x8*)(xbf + ((size_t)(b * S_ + q0 + lr)) * D_ + h * DH_ + lg * 8);
#pragma unroll
    for (int j = 0; j < 8; j++) {
      int dj = lg * 8 + j;
      float wq = WQ[((size_t)(layer * H_ + h)) * 1024 + dj * 33];
      float wk = WK[((size_t)(layer * H_ + h)) * 1024 + dj * 33];
      aq[j] = (short)f2bf(bf2f((unsigned short)xq[j]) * wq * wk * scale);
    }
  }
  float dvo[2];
#pragma unroll
  for (int fs = 0; fs < 2; fs++) {
    int fh = fs * 16 + lr;
    int fc = h * DH_ + fh;
    dvo[fs] = WV[((size_t)(layer * H_ + h)) * 1024 + fh * 33] *
              Om[(size_t)layer * 65536 + (size_t)fc * 257];
  }

  f32x4 accPV[2];
  accPV[0] = (f32x4){0.f, 0.f, 0.f, 0.f};
  accPV[1] = (f32x4){0.f, 0.f, 0.f, 0.f};
  float rsum[4] = {0.f, 0.f, 0.f, 0.f};

  const unsigned short* xk_base = xbf + ((size_t)b * S_) * D_ + h * DH_ + lg * 8;
  const unsigned short* vT_base = xnT + ((size_t)(b * D_ + h * DH_)) * S_;

  bf16x8 qkb[4];
#pragma unroll
  for (int c = 0; c < 4; c++)
    qkb[c] = *(const bf16x8*)(xk_base + (size_t)(c * 16 + lr) * D_);

  for (int kt = 0; kt < 16; kt++) {
    int k0 = kt * 64;
    bf16x8 pvb[2][2];
#pragma unroll
    for (int fs = 0; fs < 2; fs++)
#pragma unroll
      for (int kc = 0; kc < 2; kc++)
        pvb[fs][kc] = *(const bf16x8*)(vT_base + (size_t)(fs * 16 + lr) * S_ +
                                       k0 + kc * 32 + lg * 8);
    f32x4 s[4];
#pragma unroll
    for (int c = 0; c < 4; c++)
      s[c] = __builtin_amdgcn_mfma_f32_16x16x32_bf16(aq, qkb[c],
                (f32x4){0.f, 0.f, 0.f, 0.f}, 0, 0, 0);
    int ktn = kt < 15 ? kt + 1 : 15;
#pragma unroll
    for (int c = 0; c < 4; c++)
      qkb[c] = *(const bf16x8*)(xk_base + (size_t)(ktn * 64 + c * 16 + lr) * D_);
#pragma unroll
    for (int c = 0; c < 4; c++)
#pragma unroll
      for (int r = 0; r < 4; r++) {
        float p = __expf(s[c][r]);
        rsum[r] += p;
        P_lds[w][lg * 4 + r][c * 16 + lr] = f2bf(p);
      }
#pragma unroll
    for (int kc = 0; kc < 2; kc++) {
      bf16x8 pa = *(const bf16x8*)(&P_lds[w][lr][kc * 32 + lg * 8]);
#pragma unroll
      for (int fs = 0; fs < 2; fs++)
        accPV[fs] = __builtin_amdgcn_mfma_f32_16x16x32_bf16(pa, pvb[fs][kc],
                       accPV[fs], 0, 0, 0);
    }
  }

  float inv[4];
#pragma unroll
  for (int r = 0; r < 4; r++) {
    float v = rsum[r];
    v += __shfl_xor(v, 1, 64);
    v += __shfl_xor(v, 2, 64);
    v += __shfl_xor(v, 4, 64);
    v += __shfl_xor(v, 8, 64);
    inv[r] = 1.f / v;
  }
  // attention out -> LDS Aa (swizzled [16][256], BKB=512)
#pragma unroll
  for (int fs = 0; fs < 2; fs++)
#pragma unroll
    for (int r = 0; r < 4; r++) {
      float val = accPV[fs][r] * inv[r] * dvo[fs];
      int row = lg * 4 + r, col = h * DH_ + fs * 16 + lr;
      int byte = (row * 512 + col * 2) ^ ((row & 7) << 4);
      *(unsigned short*)((char*)Aa + byte) = f2bf(val);
    }
  __syncthreads();   // Aa visible to all waves; W panel 0 drained

  // ================= MLP: 12 panels (3 gemms x 4 k-steps), prefetch pipeline ====
  int lr16 = lr;
  f32x4 acc[2];
  acc[0] = (f32x4){0.f, 0.f, 0.f, 0.f};
  acc[1] = (f32x4){0.f, 0.f, 0.f, 0.f};
  const unsigned short* Asrc = Aa;

  for (int p = 0; p < 12; ++p) {
    if (p < 11) {
      int pn = p + 1;
      stage_tile_swz<256, 64, 8>(Wl + (size_t)(pn >> 2) * 65536 + (pn & 3) * 64,
                                 256, Bp[pn & 1], w, lane);
    }
    int kk0 = (p & 3) * 64;
#pragma unroll
    for (int kk = 0; kk < 64; kk += 32) {
      bf16x8 a = lds_frag<512>(Asrc, lr16, (kk0 + kk) * 2 + lg * 16);
#pragma unroll
      for (int j = 0; j < 2; j++) {
        bf16x8 bfg = lds_frag<128>(Bp[p & 1], w * 32 + j * 16 + lr16, kk * 2 + lg * 16);
        acc[j] = __builtin_amdgcn_mfma_f32_16x16x32_bf16(a, bfg, acc[j], 0, 0, 0);
      }
    }
    if (p == 3 || p == 7) {
      const float* bias = (p == 3) ? b1 : b2;
      unsigned short* dst = (p == 3) ? Ab : Ab2;
#pragma unroll
      for (int j = 0; j < 2; j++) {
        int col = w * 32 + j * 16 + lr16;
        float bv = bias[col];
#pragma unroll
        for (int r = 0; r < 4; r++) {
          float v = acc[j][r] + bv;
          v = 0.5f * v * (1.f + erff(v * 0.70710678118654752f));
          int row = lg * 4 + r;
          int byte = (row * 512 + col * 2) ^ ((row & 7) << 4);
          *(unsigned short*)((char*)dst + byte) = f2bf(v);
        }
      }
      acc[0] = (f32x4){0.f, 0.f, 0.f, 0.f};
      acc[1] = (f32x4){0.f, 0.f, 0.f, 0.f};
      Asrc = (p == 3) ? Ab : Ab2;
    }
    __syncthreads();
  }

  // ---- final epilogue: bias3 + residual (+ next-layer LN dual emit) ----
#pragma unroll
  for (int j = 0; j < 2; j++) {
    int col = w * 32 + j * 16 + lr16;
    float bv = b3[col];
#pragma unroll
    for (int r = 0; r < 4; r++) {
      int row = lg * 4 + r; int grow = r0 + row;
      float v = acc[j][r] + bv + x[(size_t)grow * D_ + col];
      if constexpr (LAST) {
        actB[(size_t)grow * D_ + col] = f2bf(v);
      } else {
        x[(size_t)grow * D_ + col] = v;
        xf[row][col] = v;
      }
    }
  }

  if constexpr (!LAST) {
    __syncthreads();
#pragma unroll
    for (int rr = 0; rr < 2; rr++) {
      int row = w * 2 + rr; int grow = r0 + row;
      f32x4 v = *(const f32x4*)&xf[row][lane * 4];
      float s = v[0] + v[1] + v[2] + v[3];
      float ss = v[0]*v[0] + v[1]*v[1] + v[2]*v[2] + v[3]*v[3];
#pragma unroll
      for (int off = 1; off < 64; off <<= 1) {
        s  += __shfl_xor(s, off, 64);
        ss += __shfl_xor(ss, off, 64);
      }
      float mean = s * (1.f / D_);
      float var = ss * (1.f / D_) - mean * mean;
      float rinv = rsqrtf(var + 1e-5f);
      float4 g4 = *(const float4*)(lngN + lane * 4);
      float4 b4 = *(const float4*)(lnbN + lane * 4);
      ushort4 o;
      o.x = f2bf((v[0] - mean) * rinv * g4.x + b4.x);
      o.y = f2bf((v[1] - mean) * rinv * g4.y + b4.y);
      o.z = f2bf((v[2] - mean) * rinv * g4.z + b4.z);
      o.w = f2bf((v[3] - mean) * rinv * g4.w + b4.w);
      *(ushort4*)(xbfN + (size_t)grow * D_ + lane * 4) = o;
      if (lane == 0) { mrow[row] = mean; rrow[row] = rinv; }
    }
    __syncthreads();
    int d = tid & 255, half = tid >> 8;
    float gd = lngN[d], bd = lnbN[d];
    int bb = r0 >> 10, s0 = r0 & 1023;
    bf16x8 o8;
#pragma unroll
    for (int k = 0; k < 8; k++) {
      int srow = half * 8 + k;
      o8[k] = (short)f2bf((xf[srow][d] - mrow[srow]) * rrow[srow] * gd + bd);
    }
    *(bf16x8*)(xnTN + ((size_t)(bb * 256 + d)) * S_ + s0 + half * 8) = o8;
  }
}

// ---------------- logits GEMM (round-16 best): B-in-regs + nt + vmcnt(4) ---------
__global__ __launch_bounds__(512) void k_logits(
    const unsigned short* __restrict__ A,    // bf16 [4096][256]
    const float* __restrict__ logitW,        // f32 [256][32000]
    float* __restrict__ C) {
  __shared__ __align__(16) unsigned short Bs[128 * 256];    // 64 KB (stage only)
  __shared__ __align__(16) unsigned short As[2][64 * 256];  // 2 x 32 KB

  int tid = threadIdx.x, lane = tid & 63, w = tid >> 6;
  int wm = w >> 2, wn = w & 3;               // 2 (row-groups) x 4 (col-groups)
  int lr = lane & 15, lg = lane >> 4;
  int bn0 = blockIdx.x * 128;

  // issue A tile 0 stage first (async; latency hides under the B-stage)
  stage_tile_swz<64, 256, 8>(A, 256, As[0], w, lane);

  // B-stage: transpose + convert logitW -> Bs [row=v][k] bf16, swizzled (BKB=512)
  {
    int c = tid & 127;          // col within slab (v - bn0)
    int kp = tid >> 7;          // 0..3
    for (int it = 0; it < 32; ++it) {
      int k = it * 8 + kp * 2;
      float f0 = logitW[(size_t)k * V_ + bn0 + c];
      float f1 = logitW[(size_t)(k + 1) * V_ + bn0 + c];
      unsigned pack = (unsigned)f2bf(f0) | ((unsigned)f2bf(f1) << 16);
      int byte = (c * 512 + k * 2) ^ ((c & 7) << 4);
      *(unsigned*)((char*)Bs + byte) = pack;
    }
  }
  __syncthreads();

  // hoist B fragments to registers (constant across all 64 t-iterations)
  bf16x8 breg[2][8];
#pragma unroll
  for (int j = 0; j < 2; j++)
#pragma unroll
    for (int ks = 0; ks < 8; ks++)
      breg[j][ks] = lds_frag<512>(Bs, wn * 32 + j * 16 + lr, ks * 64 + lg * 16);

  for (int t = 0; t < 64; ++t) {
    int cur = t & 1;
    if (t < 63)
      stage_tile_swz<64, 256, 8>(A + (size_t)(t + 1) * 64 * 256, 256, As[cur ^ 1], w, lane);

    f32x4 acc[2][2];
#pragma unroll
    for (int i = 0; i < 2; i++)
#pragma unroll
      for (int j = 0; j < 2; j++) acc[i][j] = (f32x4){0.f, 0.f, 0.f, 0.f};

#pragma unroll
    for (int ks = 0; ks < 8; ks++) {
      bf16x8 af[2];
#pragma unroll
      for (int i = 0; i < 2; i++)
        af[i] = lds_frag<512>(As[cur], wm * 32 + i * 16 + lr, ks * 64 + lg * 16);
      // swapped operands: lane = A-row (lr), regs = 4 vocab cols
#pragma unroll
      for (int i = 0; i < 2; i++)
#pragma unroll
        for (int j = 0; j < 2; j++)
          acc[i][j] = __builtin_amdgcn_mfma_f32_16x16x32_bf16(breg[j][ks], af[i], acc[i][j], 0, 0, 0);
    }

    int r0 = t * 64;
#pragma unroll
    for (int i = 0; i < 2; i++)
#pragma unroll
      for (int j = 0; j < 2; j++) {
        int row = r0 + wm * 32 + i * 16 + lr;
        int colb = bn0 + wn * 32 + j * 16 + lg * 4;
        __builtin_nontemporal_store(acc[i][j], (f32x4*)(C + (size_t)row * V_ + colb));
      }

    // counted vmcnt: wait own loads(t+1) (oldest), leave stores in flight
    asm volatile("s_waitcnt vmcnt(4)" ::: "memory");
    __builtin_amdgcn_sched_barrier(0);
    __builtin_amdgcn_s_barrier();
  }
}

// ---------------- launch ----------------
extern "C" void kernel_launch(void* const* d_in, const int* in_sizes, int n_in,
                              void* d_out, int out_size, void* d_ws, size_t ws_size,
                              hipStream_t stream) {
  const int*   X      = (const int*)d_in[0];
  const float* emb    = (const float*)d_in[1];
  const float* WQ     = (const float*)d_in[2];
  const float* WK     = (const float*)d_in[3];
  const float* WV     = (const float*)d_in[4];
  const float* Om     = (const float*)d_in[5];
  const float* lng    = (const float*)d_in[6];
  const float* lnb    = (const float*)d_in[7];
  const float* w1     = (const float*)d_in[8];
  const float* b1     = (const float*)d_in[9];
  const float* w2     = (const float*)d_in[10];
  const float* b2     = (const float*)d_in[11];
  const float* w3     = (const float*)d_in[12];
  const float* b3     = (const float*)d_in[13];
  const float* logitW = (const float*)d_in[14];
  float* out = (float*)d_out;
  char* ws = (char*)d_ws;

  constexpr size_t MB = 1024u * 1024;
  float* x  = (float*)(ws);                                    // 4 MB
  unsigned short* xbf0 = (unsigned short*)(ws + 4 * MB);       // 2 MB
  unsigned short* xbf1 = (unsigned short*)(ws + 6 * MB);       // 2 MB
  unsigned short* xnT0 = (unsigned short*)(ws + 8 * MB);       // 2 MB
  unsigned short* xnT1 = (unsigned short*)(ws + 10 * MB);      // 2 MB
  unsigned short* actB = (unsigned short*)(ws + 12 * MB);      // 2 MB
  unsigned short* mlpW = (unsigned short*)(ws + 14 * MB);      // 1.5 MB

  // fused prep: embed+LN0 (256 blocks) + MLP weight tconv (192 blocks)
  k_prep<<<448, 512, 0, stream>>>(X, emb, lng, lnb, x, xbf0, xnT0, w1, w2, w3, mlpW);

  for (int l = 0; l < L_; l++) {
    const unsigned short* xbfI = (l & 1) ? xbf1 : xbf0;
    const unsigned short* xnTI = (l & 1) ? xnT1 : xnT0;
    unsigned short* xbfO = (l & 1) ? xbf0 : xbf1;
    unsigned short* xnTO = (l & 1) ? xnT0 : xnT1;
    if (l < L_ - 1) {
      k_layer<0><<<256, 512, 0, stream>>>(
          xbfI, xnTI, WQ, WK, WV, Om, mlpW + (size_t)(l * 3) * 65536,
          b1 + (size_t)l * D_, b2 + (size_t)l * D_, b3 + (size_t)l * D_, x,
          lng + (size_t)(l + 1) * D_, lnb + (size_t)(l + 1) * D_,
          xbfO, xnTO, nullptr, l);
    } else {
      k_layer<1><<<256, 512, 0, stream>>>(
          xbfI, xnTI, WQ, WK, WV, Om, mlpW + (size_t)(l * 3) * 65536,
          b1 + (size_t)l * D_, b2 + (size_t)l * D_, b3 + (size_t)l * D_, x,
          nullptr, nullptr, nullptr, nullptr, actB, l);
    }
  }

  // logits: round-16 best (B-in-registers, nt stores, counted vmcnt)
  k_logits<<<250, 512, 0, stream>>>(actB, logitW, out);
}

// Round 21
// 323.612 us; speedup vs baseline: 1.3365x; 1.0160x over previous
//
#include <hip/hip_runtime.h>
#include <hip/hip_bf16.h>
#include <cstdint>
#include <cstddef>

#define B_ 4
#define S_ 1024
#define V_ 32000
#define D_ 256
#define H_ 8
#define DH_ 32
#define L_ 4
#define MROWS (B_*S_)

typedef __attribute__((ext_vector_type(8))) short bf16x8;
typedef __attribute__((ext_vector_type(4))) float f32x4;

__device__ __forceinline__ unsigned short f2bf(float f) {
  union { float f; unsigned u; } c; c.f = f;
  unsigned u = c.u;
  u += 0x7fff + ((u >> 16) & 1);   // round-to-nearest-even
  return (unsigned short)(u >> 16);
}
__device__ __forceinline__ float bf2f(unsigned short u) {
  union { unsigned u; float f; } c; c.u = ((unsigned)u) << 16; return c.f;
}

// async global->LDS, 16B per lane; LDS dest is wave-uniform base + lane*16
__device__ __forceinline__ void gload16(const unsigned short* g, unsigned short* l) {
  __builtin_amdgcn_global_load_lds(
      (const __attribute__((address_space(1))) void*)g,
      (__attribute__((address_space(3))) void*)l, 16, 0, 0);
}

// ---- XOR-swizzled LDS tiles: lds[row][inner ^ ((row&7)<<4)] = g[row][inner]
template<int BM, int BK, int NW>
__device__ __forceinline__ void stage_tile_swz(const unsigned short* __restrict__ g, int ldg,
                                               unsigned short* lds, int wave, int lane) {
  constexpr int CH  = BM * BK * 2 / 1024;   // 1KB chunks
  constexpr int BKB = BK * 2;               // bytes per row
#pragma unroll
  for (int t = 0; t < CH / NW; ++t) {
    int c = wave + t * NW;
    int byte  = c * 1024 + lane * 16;
    int row   = byte / BKB;
    int inner = (byte % BKB) ^ ((row & 7) << 4);
    gload16(g + (size_t)row * ldg + (inner >> 1), lds + c * 512);
  }
}

// swizzled 16B fragment read: row-major [*][BKB/2] tile, kbytes multiple of 16
template<int BKB>
__device__ __forceinline__ bf16x8 lds_frag(const unsigned short* base, int row, int kbytes) {
  int b = (row * BKB + kbytes) ^ ((row & 7) << 4);
  return *(const bf16x8*)((const char*)base + b);
}

// ---------------- fused prep: embln (blocks 0..255) + MLP W tconv (256..447) ------
__global__ __launch_bounds__(512) void k_prep(
    const int* __restrict__ X, const float* __restrict__ emb,
    const float* __restrict__ lng, const float* __restrict__ lnb,
    float* __restrict__ x, unsigned short* __restrict__ xbf,
    unsigned short* __restrict__ xnT,
    const float* __restrict__ w1, const float* __restrict__ w2,
    const float* __restrict__ w3, unsigned short* __restrict__ mlpW) {
  int tid = threadIdx.x;
  if (blockIdx.x < 256) {
    __shared__ __align__(16) float xf[16][264];
    __shared__ float mrow[16], rrow[16];
    int r0 = blockIdx.x * 16;
    int w = tid >> 6, lane = tid & 63;
#pragma unroll
    for (int rr = 0; rr < 2; rr++) {
      int row = w * 2 + rr; int grow = r0 + row;
      int tok = X[grow];
      f32x4 v = *(const f32x4*)(emb + (size_t)tok * D_ + lane * 4);
      *(f32x4*)(x + (size_t)grow * D_ + lane * 4) = v;
      *(f32x4*)&xf[row][lane * 4] = v;
      float s = v[0] + v[1] + v[2] + v[3];
      float ss = v[0]*v[0] + v[1]*v[1] + v[2]*v[2] + v[3]*v[3];
#pragma unroll
      for (int off = 1; off < 64; off <<= 1) {
        s  += __shfl_xor(s, off, 64);
        ss += __shfl_xor(ss, off, 64);
      }
      float mean = s * (1.f / D_);
      float var = ss * (1.f / D_) - mean * mean;
      float rinv = rsqrtf(var + 1e-5f);
      float4 g4 = *(const float4*)(lng + lane * 4);
      float4 b4 = *(const float4*)(lnb + lane * 4);
      ushort4 o;
      o.x = f2bf((v[0] - mean) * rinv * g4.x + b4.x);
      o.y = f2bf((v[1] - mean) * rinv * g4.y + b4.y);
      o.z = f2bf((v[2] - mean) * rinv * g4.z + b4.z);
      o.w = f2bf((v[3] - mean) * rinv * g4.w + b4.w);
      *(ushort4*)(xbf + (size_t)grow * D_ + lane * 4) = o;
      if (lane == 0) { mrow[row] = mean; rrow[row] = rinv; }
    }
    __syncthreads();
    int d = tid & 255, half = tid >> 8;
    float gd = lng[d], bd = lnb[d];
    int bb = r0 >> 10, s0 = r0 & 1023;
    bf16x8 o8;
#pragma unroll
    for (int k = 0; k < 8; k++) {
      int srow = half * 8 + k;
      o8[k] = (short)f2bf((xf[srow][d] - mrow[srow]) * rrow[srow] * gd + bd);
    }
    *(bf16x8*)(xnT + ((size_t)(bb * 256 + d)) * S_ + s0 + half * 8) = o8;
  } else {
    __shared__ float tile[64][65];
    int idx = blockIdx.x - 256;               // 0..191
    int z = idx >> 4;                         // 0..11  (l*3+mm)
    int rem = idx & 15;
    int r0 = (rem >> 2) * 64, c0 = (rem & 3) * 64;
    int l = z / 3, mm = z % 3;
    const float* in = (mm == 0 ? w1 : mm == 1 ? w2 : w3) + (size_t)l * 65536;
    unsigned short* out = mlpW + (size_t)z * 65536;
    int t = tid & 255;
    bool act = tid < 256;
    if (act) {
#pragma unroll
      for (int i = 0; i < 16; i++) {
        int id2 = i * 256 + t;
        int lr = id2 >> 6, lc = id2 & 63;
        tile[lr][lc] = in[(size_t)(r0 + lr) * 256 + c0 + lc];
      }
    }
    __syncthreads();
    if (act) {
#pragma unroll
      for (int i = 0; i < 16; i++) {
        int id2 = i * 256 + t;
        int lr = id2 >> 6, lc = id2 & 63;
        out[(size_t)(c0 + lr) * 256 + r0 + lc] = f2bf(tile[lc][lr]);
      }
    }
  }
}

// ---------------- fused layer: attn + 3-GEMM MLP with depth-2 panel pipeline ------
// MLP W panels now triple-buffered (96 KB), prefetch distance 2; per-panel
// barrier is counted vmcnt(4) + raw s_barrier (leaves panel p+2's loads in
// flight; waits p+1's) -- the T4 lever proven on k_logits in r16. p=3/7 add
// lgkmcnt(0) so the Ab/Ab2 ds_writes are cross-wave visible at the barrier.
template<int LAST>
__global__ __launch_bounds__(512) void k_layer(
    const unsigned short* __restrict__ xbf,   // layer input  [4096][256] bf16
    const unsigned short* __restrict__ xnT,   // layer input  [4][256][1024] bf16
    const float* __restrict__ WQ, const float* __restrict__ WK,
    const float* __restrict__ WV, const float* __restrict__ Om,
    const unsigned short* __restrict__ Wl,    // 3 x [256][256] bf16 (this layer)
    const float* __restrict__ b1, const float* __restrict__ b2, const float* __restrict__ b3,
    float* __restrict__ x,                    // residual f32
    const float* __restrict__ lngN, const float* __restrict__ lnbN,
    unsigned short* __restrict__ xbfN, unsigned short* __restrict__ xnTN,  // outputs (!LAST)
    unsigned short* __restrict__ actB,        // output (LAST)
    int layer) {
  __shared__ __align__(16) unsigned short P_lds[8][16][72];
  __shared__ __align__(16) unsigned short Aa[16 * 256];
  __shared__ __align__(16) unsigned short Ab[16 * 256];
  __shared__ __align__(16) unsigned short Ab2[16 * 256];
  __shared__ __align__(16) unsigned short Bp[3][256 * 64];
  __shared__ __align__(16) float xf[16][264];
  __shared__ float mrow[16], rrow[16];

  int b = blockIdx.x >> 6;
  int q0 = (blockIdx.x & 63) << 4;
  int r0 = blockIdx.x * 16;                  // == b*S + q0
  int tid = threadIdx.x;
  int w = tid >> 6, lane = tid & 63;
  int lr = lane & 15, lg = lane >> 4;
  int h = w;

  // prefetch MLP W panel 0 (drained at the post-attention barrier)
  stage_tile_swz<256, 64, 8>(Wl, 256, Bp[0], w, lane);

  // ================= attention =================
  const float scale = 0.17677669529663687f;  // 1/sqrt(32)
  bf16x8 aq;
  {
    bf16x8 xq = *(const bf16x8*)(xbf + ((size_t)(b * S_ + q0 + lr)) * D_ + h * DH_ + lg * 8);
#pragma unroll
    for (int j = 0; j < 8; j++) {
      int dj = lg * 8 + j;
      float wq = WQ[((size_t)(layer * H_ + h)) * 1024 + dj * 33];
      float wk = WK[((size_t)(layer * H_ + h)) * 1024 + dj * 33];
      aq[j] = (short)f2bf(bf2f((unsigned short)xq[j]) * wq * wk * scale);
    }
  }
  float dvo[2];
#pragma unroll
  for (int fs = 0; fs < 2; fs++) {
    int fh = fs * 16 + lr;
    int fc = h * DH_ + fh;
    dvo[fs] = WV[((size_t)(layer * H_ + h)) * 1024 + fh * 33] *
              Om[(size_t)layer * 65536 + (size_t)fc * 257];
  }

  f32x4 accPV[2];
  accPV[0] = (f32x4){0.f, 0.f, 0.f, 0.f};
  accPV[1] = (f32x4){0.f, 0.f, 0.f, 0.f};
  float rsum[4] = {0.f, 0.f, 0.f, 0.f};

  const unsigned short* xk_base = xbf + ((size_t)b * S_) * D_ + h * DH_ + lg * 8;
  const unsigned short* vT_base = xnT + ((size_t)(b * D_ + h * DH_)) * S_;

  bf16x8 qkb[4];
#pragma unroll
  for (int c = 0; c < 4; c++)
    qkb[c] = *(const bf16x8*)(xk_base + (size_t)(c * 16 + lr) * D_);

  for (int kt = 0; kt < 16; kt++) {
    int k0 = kt * 64;
    bf16x8 pvb[2][2];
#pragma unroll
    for (int fs = 0; fs < 2; fs++)
#pragma unroll
      for (int kc = 0; kc < 2; kc++)
        pvb[fs][kc] = *(const bf16x8*)(vT_base + (size_t)(fs * 16 + lr) * S_ +
                                       k0 + kc * 32 + lg * 8);
    f32x4 s[4];
#pragma unroll
    for (int c = 0; c < 4; c++)
      s[c] = __builtin_amdgcn_mfma_f32_16x16x32_bf16(aq, qkb[c],
                (f32x4){0.f, 0.f, 0.f, 0.f}, 0, 0, 0);
    int ktn = kt < 15 ? kt + 1 : 15;
#pragma unroll
    for (int c = 0; c < 4; c++)
      qkb[c] = *(const bf16x8*)(xk_base + (size_t)(ktn * 64 + c * 16 + lr) * D_);
#pragma unroll
    for (int c = 0; c < 4; c++)
#pragma unroll
      for (int r = 0; r < 4; r++) {
        float p = __expf(s[c][r]);
        rsum[r] += p;
        P_lds[w][lg * 4 + r][c * 16 + lr] = f2bf(p);
      }
#pragma unroll
    for (int kc = 0; kc < 2; kc++) {
      bf16x8 pa = *(const bf16x8*)(&P_lds[w][lr][kc * 32 + lg * 8]);
#pragma unroll
      for (int fs = 0; fs < 2; fs++)
        accPV[fs] = __builtin_amdgcn_mfma_f32_16x16x32_bf16(pa, pvb[fs][kc],
                       accPV[fs], 0, 0, 0);
    }
  }

  float inv[4];
#pragma unroll
  for (int r = 0; r < 4; r++) {
    float v = rsum[r];
    v += __shfl_xor(v, 1, 64);
    v += __shfl_xor(v, 2, 64);
    v += __shfl_xor(v, 4, 64);
    v += __shfl_xor(v, 8, 64);
    inv[r] = 1.f / v;
  }
  // attention out -> LDS Aa (swizzled [16][256], BKB=512)
#pragma unroll
  for (int fs = 0; fs < 2; fs++)
#pragma unroll
    for (int r = 0; r < 4; r++) {
      float val = accPV[fs][r] * inv[r] * dvo[fs];
      int row = lg * 4 + r, col = h * DH_ + fs * 16 + lr;
      int byte = (row * 512 + col * 2) ^ ((row & 7) << 4);
      *(unsigned short*)((char*)Aa + byte) = f2bf(val);
    }
  __syncthreads();   // Aa visible; W panel 0 loads drained (implicit vmcnt 0)

  // ================= MLP: 12 panels, triple-buffered depth-2 pipeline ====
  int lr16 = lr;
  f32x4 acc[2];
  acc[0] = (f32x4){0.f, 0.f, 0.f, 0.f};
  acc[1] = (f32x4){0.f, 0.f, 0.f, 0.f};
  const unsigned short* Asrc = Aa;

  // prefetch panel 1
  stage_tile_swz<256, 64, 8>(Wl + 64, 256, Bp[1], w, lane);

  for (int p = 0; p < 12; ++p) {
    if (p < 10) {
      int pn = p + 2;
      stage_tile_swz<256, 64, 8>(Wl + (size_t)(pn >> 2) * 65536 + (pn & 3) * 64,
                                 256, Bp[pn % 3], w, lane);
    }
    int kk0 = (p & 3) * 64;
#pragma unroll
    for (int kk = 0; kk < 64; kk += 32) {
      bf16x8 a = lds_frag<512>(Asrc, lr16, (kk0 + kk) * 2 + lg * 16);
#pragma unroll
      for (int j = 0; j < 2; j++) {
        bf16x8 bfg = lds_frag<128>(Bp[p % 3], w * 32 + j * 16 + lr16, kk * 2 + lg * 16);
        acc[j] = __builtin_amdgcn_mfma_f32_16x16x32_bf16(a, bfg, acc[j], 0, 0, 0);
      }
    }
    if (p == 3 || p == 7) {
      const float* bias = (p == 3) ? b1 : b2;
      unsigned short* dst = (p == 3) ? Ab : Ab2;
#pragma unroll
      for (int j = 0; j < 2; j++) {
        int col = w * 32 + j * 16 + lr16;
        float bv = bias[col];
#pragma unroll
        for (int r = 0; r < 4; r++) {
          float v = acc[j][r] + bv;
          v = 0.5f * v * (1.f + erff(v * 0.70710678118654752f));
          int row = lg * 4 + r;
          int byte = (row * 512 + col * 2) ^ ((row & 7) << 4);
          *(unsigned short*)((char*)dst + byte) = f2bf(v);
        }
      }
      acc[0] = (f32x4){0.f, 0.f, 0.f, 0.f};
      acc[1] = (f32x4){0.f, 0.f, 0.f, 0.f};
      Asrc = (p == 3) ? Ab : Ab2;
      asm volatile("s_waitcnt lgkmcnt(0)" ::: "memory");  // Ab/Ab2 visible at barrier
    }
    // wait panel p+1's loads (oldest); leave p+2's in flight
    if (p < 10) asm volatile("s_waitcnt vmcnt(4)" ::: "memory");
    else        asm volatile("s_waitcnt vmcnt(0)" ::: "memory");
    __builtin_amdgcn_sched_barrier(0);
    __builtin_amdgcn_s_barrier();
  }

  // ---- final epilogue: bias3 + residual (+ next-layer LN dual emit) ----
#pragma unroll
  for (int j = 0; j < 2; j++) {
    int col = w * 32 + j * 16 + lr16;
    float bv = b3[col];
#pragma unroll
    for (int r = 0; r < 4; r++) {
      int row = lg * 4 + r; int grow = r0 + row;
      float v = acc[j][r] + bv + x[(size_t)grow * D_ + col];
      if constexpr (LAST) {
        actB[(size_t)grow * D_ + col] = f2bf(v);
      } else {
        x[(size_t)grow * D_ + col] = v;
        xf[row][col] = v;
      }
    }
  }

  if constexpr (!LAST) {
    __syncthreads();
#pragma unroll
    for (int rr = 0; rr < 2; rr++) {
      int row = w * 2 + rr; int grow = r0 + row;
      f32x4 v = *(const f32x4*)&xf[row][lane * 4];
      float s = v[0] + v[1] + v[2] + v[3];
      float ss = v[0]*v[0] + v[1]*v[1] + v[2]*v[2] + v[3]*v[3];
#pragma unroll
      for (int off = 1; off < 64; off <<= 1) {
        s  += __shfl_xor(s, off, 64);
        ss += __shfl_xor(ss, off, 64);
      }
      float mean = s * (1.f / D_);
      float var = ss * (1.f / D_) - mean * mean;
      float rinv = rsqrtf(var + 1e-5f);
      float4 g4 = *(const float4*)(lngN + lane * 4);
      float4 b4 = *(const float4*)(lnbN + lane * 4);
      ushort4 o;
      o.x = f2bf((v[0] - mean) * rinv * g4.x + b4.x);
      o.y = f2bf((v[1] - mean) * rinv * g4.y + b4.y);
      o.z = f2bf((v[2] - mean) * rinv * g4.z + b4.z);
      o.w = f2bf((v[3] - mean) * rinv * g4.w + b4.w);
      *(ushort4*)(xbfN + (size_t)grow * D_ + lane * 4) = o;
      if (lane == 0) { mrow[row] = mean; rrow[row] = rinv; }
    }
    __syncthreads();
    int d = tid & 255, half = tid >> 8;
    float gd = lngN[d], bd = lnbN[d];
    int bb = r0 >> 10, s0 = r0 & 1023;
    bf16x8 o8;
#pragma unroll
    for (int k = 0; k < 8; k++) {
      int srow = half * 8 + k;
      o8[k] = (short)f2bf((xf[srow][d] - mrow[srow]) * rrow[srow] * gd + bd);
    }
    *(bf16x8*)(xnTN + ((size_t)(bb * 256 + d)) * S_ + s0 + half * 8) = o8;
  }
}

// ---------------- logits GEMM (round-16 best): B-in-regs + nt + vmcnt(4) ---------
__global__ __launch_bounds__(512) void k_logits(
    const unsigned short* __restrict__ A,    // bf16 [4096][256]
    const float* __restrict__ logitW,        // f32 [256][32000]
    float* __restrict__ C) {
  __shared__ __align__(16) unsigned short Bs[128 * 256];    // 64 KB (stage only)
  __shared__ __align__(16) unsigned short As[2][64 * 256];  // 2 x 32 KB

  int tid = threadIdx.x, lane = tid & 63, w = tid >> 6;
  int wm = w >> 2, wn = w & 3;               // 2 (row-groups) x 4 (col-groups)
  int lr = lane & 15, lg = lane >> 4;
  int bn0 = blockIdx.x * 128;

  // issue A tile 0 stage first (async; latency hides under the B-stage)
  stage_tile_swz<64, 256, 8>(A, 256, As[0], w, lane);

  // B-stage: transpose + convert logitW -> Bs [row=v][k] bf16, swizzled (BKB=512)
  {
    int c = tid & 127;          // col within slab (v - bn0)
    int kp = tid >> 7;          // 0..3
    for (int it = 0; it < 32; ++it) {
      int k = it * 8 + kp * 2;
      float f0 = logitW[(size_t)k * V_ + bn0 + c];
      float f1 = logitW[(size_t)(k + 1) * V_ + bn0 + c];
      unsigned pack = (unsigned)f2bf(f0) | ((unsigned)f2bf(f1) << 16);
      int byte = (c * 512 + k * 2) ^ ((c & 7) << 4);
      *(unsigned*)((char*)Bs + byte) = pack;
    }
  }
  __syncthreads();

  // hoist B fragments to registers (constant across all 64 t-iterations)
  bf16x8 breg[2][8];
#pragma unroll
  for (int j = 0; j < 2; j++)
#pragma unroll
    for (int ks = 0; ks < 8; ks++)
      breg[j][ks] = lds_frag<512>(Bs, wn * 32 + j * 16 + lr, ks * 64 + lg * 16);

  for (int t = 0; t < 64; ++t) {
    int cur = t & 1;
    if (t < 63)
      stage_tile_swz<64, 256, 8>(A + (size_t)(t + 1) * 64 * 256, 256, As[cur ^ 1], w, lane);

    f32x4 acc[2][2];
#pragma unroll
    for (int i = 0; i < 2; i++)
#pragma unroll
      for (int j = 0; j < 2; j++) acc[i][j] = (f32x4){0.f, 0.f, 0.f, 0.f};

#pragma unroll
    for (int ks = 0; ks < 8; ks++) {
      bf16x8 af[2];
#pragma unroll
      for (int i = 0; i < 2; i++)
        af[i] = lds_frag<512>(As[cur], wm * 32 + i * 16 + lr, ks * 64 + lg * 16);
      // swapped operands: lane = A-row (lr), regs = 4 vocab cols
#pragma unroll
      for (int i = 0; i < 2; i++)
#pragma unroll
        for (int j = 0; j < 2; j++)
          acc[i][j] = __builtin_amdgcn_mfma_f32_16x16x32_bf16(breg[j][ks], af[i], acc[i][j], 0, 0, 0);
    }

    int r0 = t * 64;
#pragma unroll
    for (int i = 0; i < 2; i++)
#pragma unroll
      for (int j = 0; j < 2; j++) {
        int row = r0 + wm * 32 + i * 16 + lr;
        int colb = bn0 + wn * 32 + j * 16 + lg * 4;
        __builtin_nontemporal_store(acc[i][j], (f32x4*)(C + (size_t)row * V_ + colb));
      }

    // counted vmcnt: wait own loads(t+1) (oldest), leave stores in flight
    asm volatile("s_waitcnt vmcnt(4)" ::: "memory");
    __builtin_amdgcn_sched_barrier(0);
    __builtin_amdgcn_s_barrier();
  }
}

// ---------------- launch ----------------
extern "C" void kernel_launch(void* const* d_in, const int* in_sizes, int n_in,
                              void* d_out, int out_size, void* d_ws, size_t ws_size,
                              hipStream_t stream) {
  const int*   X      = (const int*)d_in[0];
  const float* emb    = (const float*)d_in[1];
  const float* WQ     = (const float*)d_in[2];
  const float* WK     = (const float*)d_in[3];
  const float* WV     = (const float*)d_in[4];
  const float* Om     = (const float*)d_in[5];
  const float* lng    = (const float*)d_in[6];
  const float* lnb    = (const float*)d_in[7];
  const float* w1     = (const float*)d_in[8];
  const float* b1     = (const float*)d_in[9];
  const float* w2     = (const float*)d_in[10];
  const float* b2     = (const float*)d_in[11];
  const float* w3     = (const float*)d_in[12];
  const float* b3     = (const float*)d_in[13];
  const float* logitW = (const float*)d_in[14];
  float* out = (float*)d_out;
  char* ws = (char*)d_ws;

  constexpr size_t MB = 1024u * 1024;
  float* x  = (float*)(ws);                                    // 4 MB
  unsigned short* xbf0 = (unsigned short*)(ws + 4 * MB);       // 2 MB
  unsigned short* xbf1 = (unsigned short*)(ws + 6 * MB);       // 2 MB
  unsigned short* xnT0 = (unsigned short*)(ws + 8 * MB);       // 2 MB
  unsigned short* xnT1 = (unsigned short*)(ws + 10 * MB);      // 2 MB
  unsigned short* actB = (unsigned short*)(ws + 12 * MB);      // 2 MB
  unsigned short* mlpW = (unsigned short*)(ws + 14 * MB);      // 1.5 MB

  // fused prep: embed+LN0 (256 blocks) + MLP weight tconv (192 blocks)
  k_prep<<<448, 512, 0, stream>>>(X, emb, lng, lnb, x, xbf0, xnT0, w1, w2, w3, mlpW);

  for (int l = 0; l < L_; l++) {
    const unsigned short* xbfI = (l & 1) ? xbf1 : xbf0;
    const unsigned short* xnTI = (l & 1) ? xnT1 : xnT0;
    unsigned short* xbfO = (l & 1) ? xbf0 : xbf1;
    unsigned short* xnTO = (l & 1) ? xnT0 : xnT1;
    if (l < L_ - 1) {
      k_layer<0><<<256, 512, 0, stream>>>(
          xbfI, xnTI, WQ, WK, WV, Om, mlpW + (size_t)(l * 3) * 65536,
          b1 + (size_t)l * D_, b2 + (size_t)l * D_, b3 + (size_t)l * D_, x,
          lng + (size_t)(l + 1) * D_, lnb + (size_t)(l + 1) * D_,
          xbfO, xnTO, nullptr, l);
    } else {
      k_layer<1><<<256, 512, 0, stream>>>(
          xbfI, xnTI, WQ, WK, WV, Om, mlpW + (size_t)(l * 3) * 65536,
          b1 + (size_t)l * D_, b2 + (size_t)l * D_, b3 + (size_t)l * D_, x,
          nullptr, nullptr, nullptr, nullptr, actB, l);
    }
  }

  // logits: round-16 best (B-in-registers, nt stores, counted vmcnt)
  k_logits<<<250, 512, 0, stream>>>(actB, logitW, out);
}

// Round 22
// 318.286 us; speedup vs baseline: 1.3588x; 1.0167x over previous
//
#include <hip/hip_runtime.h>
#include <hip/hip_bf16.h>
#include <cstdint>
#include <cstddef>

#define B_ 4
#define S_ 1024
#define V_ 32000
#define D_ 256
#define H_ 8
#define DH_ 32
#define L_ 4
#define MROWS (B_*S_)

typedef __attribute__((ext_vector_type(8))) short bf16x8;
typedef __attribute__((ext_vector_type(4))) float f32x4;

__device__ __forceinline__ unsigned short f2bf(float f) {
  union { float f; unsigned u; } c; c.f = f;
  unsigned u = c.u;
  u += 0x7fff + ((u >> 16) & 1);   // round-to-nearest-even
  return (unsigned short)(u >> 16);
}
__device__ __forceinline__ float bf2f(unsigned short u) {
  union { unsigned u; float f; } c; c.u = ((unsigned)u) << 16; return c.f;
}

// async global->LDS, 16B per lane; LDS dest is wave-uniform base + lane*16
__device__ __forceinline__ void gload16(const unsigned short* g, unsigned short* l) {
  __builtin_amdgcn_global_load_lds(
      (const __attribute__((address_space(1))) void*)g,
      (__attribute__((address_space(3))) void*)l, 16, 0, 0);
}

// ---- XOR-swizzled LDS tiles: lds[row][inner ^ ((row&7)<<4)] = g[row][inner]
template<int BM, int BK, int NW>
__device__ __forceinline__ void stage_tile_swz(const unsigned short* __restrict__ g, int ldg,
                                               unsigned short* lds, int wave, int lane) {
  constexpr int CH  = BM * BK * 2 / 1024;   // 1KB chunks
  constexpr int BKB = BK * 2;               // bytes per row
#pragma unroll
  for (int t = 0; t < CH / NW; ++t) {
    int c = wave + t * NW;
    int byte  = c * 1024 + lane * 16;
    int row   = byte / BKB;
    int inner = (byte % BKB) ^ ((row & 7) << 4);
    gload16(g + (size_t)row * ldg + (inner >> 1), lds + c * 512);
  }
}

// swizzled 16B fragment read: row-major [*][BKB/2] tile, kbytes multiple of 16
template<int BKB>
__device__ __forceinline__ bf16x8 lds_frag(const unsigned short* base, int row, int kbytes) {
  int b = (row * BKB + kbytes) ^ ((row & 7) << 4);
  return *(const bf16x8*)((const char*)base + b);
}

// ---------------- fused prep: embln (blocks 0..255) + MLP W tconv (256..447) ------
__global__ __launch_bounds__(512) void k_prep(
    const int* __restrict__ X, const float* __restrict__ emb,
    const float* __restrict__ lng, const float* __restrict__ lnb,
    float* __restrict__ x, unsigned short* __restrict__ xbf,
    unsigned short* __restrict__ xnT,
    const float* __restrict__ w1, const float* __restrict__ w2,
    const float* __restrict__ w3, unsigned short* __restrict__ mlpW) {
  int tid = threadIdx.x;
  if (blockIdx.x < 256) {
    __shared__ __align__(16) float xf[16][264];
    __shared__ float mrow[16], rrow[16];
    int r0 = blockIdx.x * 16;
    int w = tid >> 6, lane = tid & 63;
#pragma unroll
    for (int rr = 0; rr < 2; rr++) {
      int row = w * 2 + rr; int grow = r0 + row;
      int tok = X[grow];
      f32x4 v = *(const f32x4*)(emb + (size_t)tok * D_ + lane * 4);
      *(f32x4*)(x + (size_t)grow * D_ + lane * 4) = v;
      *(f32x4*)&xf[row][lane * 4] = v;
      float s = v[0] + v[1] + v[2] + v[3];
      float ss = v[0]*v[0] + v[1]*v[1] + v[2]*v[2] + v[3]*v[3];
#pragma unroll
      for (int off = 1; off < 64; off <<= 1) {
        s  += __shfl_xor(s, off, 64);
        ss += __shfl_xor(ss, off, 64);
      }
      float mean = s * (1.f / D_);
      float var = ss * (1.f / D_) - mean * mean;
      float rinv = rsqrtf(var + 1e-5f);
      float4 g4 = *(const float4*)(lng + lane * 4);
      float4 b4 = *(const float4*)(lnb + lane * 4);
      ushort4 o;
      o.x = f2bf((v[0] - mean) * rinv * g4.x + b4.x);
      o.y = f2bf((v[1] - mean) * rinv * g4.y + b4.y);
      o.z = f2bf((v[2] - mean) * rinv * g4.z + b4.z);
      o.w = f2bf((v[3] - mean) * rinv * g4.w + b4.w);
      *(ushort4*)(xbf + (size_t)grow * D_ + lane * 4) = o;
      if (lane == 0) { mrow[row] = mean; rrow[row] = rinv; }
    }
    __syncthreads();
    int d = tid & 255, half = tid >> 8;
    float gd = lng[d], bd = lnb[d];
    int bb = r0 >> 10, s0 = r0 & 1023;
    bf16x8 o8;
#pragma unroll
    for (int k = 0; k < 8; k++) {
      int srow = half * 8 + k;
      o8[k] = (short)f2bf((xf[srow][d] - mrow[srow]) * rrow[srow] * gd + bd);
    }
    *(bf16x8*)(xnT + ((size_t)(bb * 256 + d)) * S_ + s0 + half * 8) = o8;
  } else {
    __shared__ float tile[64][65];
    int idx = blockIdx.x - 256;               // 0..191
    int z = idx >> 4;                         // 0..11  (l*3+mm)
    int rem = idx & 15;
    int r0 = (rem >> 2) * 64, c0 = (rem & 3) * 64;
    int l = z / 3, mm = z % 3;
    const float* in = (mm == 0 ? w1 : mm == 1 ? w2 : w3) + (size_t)l * 65536;
    unsigned short* out = mlpW + (size_t)z * 65536;
    int t = tid & 255;
    bool act = tid < 256;
    if (act) {
#pragma unroll
      for (int i = 0; i < 16; i++) {
        int id2 = i * 256 + t;
        int lr = id2 >> 6, lc = id2 & 63;
        tile[lr][lc] = in[(size_t)(r0 + lr) * 256 + c0 + lc];
      }
    }
    __syncthreads();
    if (act) {
#pragma unroll
      for (int i = 0; i < 16; i++) {
        int id2 = i * 256 + t;
        int lr = id2 >> 6, lc = id2 & 63;
        out[(size_t)(c0 + lr) * 256 + r0 + lc] = f2bf(tile[lc][lr]);
      }
    }
  }
}

// ---------------- fused layer: attn + 3-GEMM MLP with depth-2 panel pipeline ------
template<int LAST>
__global__ __launch_bounds__(512) void k_layer(
    const unsigned short* __restrict__ xbf,   // layer input  [4096][256] bf16
    const unsigned short* __restrict__ xnT,   // layer input  [4][256][1024] bf16
    const float* __restrict__ WQ, const float* __restrict__ WK,
    const float* __restrict__ WV, const float* __restrict__ Om,
    const unsigned short* __restrict__ Wl,    // 3 x [256][256] bf16 (this layer)
    const float* __restrict__ b1, const float* __restrict__ b2, const float* __restrict__ b3,
    float* __restrict__ x,                    // residual f32
    const float* __restrict__ lngN, const float* __restrict__ lnbN,
    unsigned short* __restrict__ xbfN, unsigned short* __restrict__ xnTN,  // outputs (!LAST)
    unsigned short* __restrict__ actB,        // output (LAST)
    int layer) {
  __shared__ __align__(16) unsigned short P_lds[8][16][72];
  __shared__ __align__(16) unsigned short Aa[16 * 256];
  __shared__ __align__(16) unsigned short Ab[16 * 256];
  __shared__ __align__(16) unsigned short Ab2[16 * 256];
  __shared__ __align__(16) unsigned short Bp[3][256 * 64];
  __shared__ __align__(16) float xf[16][264];
  __shared__ float mrow[16], rrow[16];

  int b = blockIdx.x >> 6;
  int q0 = (blockIdx.x & 63) << 4;
  int r0 = blockIdx.x * 16;                  // == b*S + q0
  int tid = threadIdx.x;
  int w = tid >> 6, lane = tid & 63;
  int lr = lane & 15, lg = lane >> 4;
  int h = w;

  // prefetch MLP W panel 0 (drained at the post-attention barrier)
  stage_tile_swz<256, 64, 8>(Wl, 256, Bp[0], w, lane);

  // ================= attention =================
  const float scale = 0.17677669529663687f;  // 1/sqrt(32)
  bf16x8 aq;
  {
    bf16x8 xq = *(const bf16x8*)(xbf + ((size_t)(b * S_ + q0 + lr)) * D_ + h * DH_ + lg * 8);
#pragma unroll
    for (int j = 0; j < 8; j++) {
      int dj = lg * 8 + j;
      float wq = WQ[((size_t)(layer * H_ + h)) * 1024 + dj * 33];
      float wk = WK[((size_t)(layer * H_ + h)) * 1024 + dj * 33];
      aq[j] = (short)f2bf(bf2f((unsigned short)xq[j]) * wq * wk * scale);
    }
  }
  float dvo[2];
#pragma unroll
  for (int fs = 0; fs < 2; fs++) {
    int fh = fs * 16 + lr;
    int fc = h * DH_ + fh;
    dvo[fs] = WV[((size_t)(layer * H_ + h)) * 1024 + fh * 33] *
              Om[(size_t)layer * 65536 + (size_t)fc * 257];
  }

  f32x4 accPV[2];
  accPV[0] = (f32x4){0.f, 0.f, 0.f, 0.f};
  accPV[1] = (f32x4){0.f, 0.f, 0.f, 0.f};
  float rsum[4] = {0.f, 0.f, 0.f, 0.f};

  const unsigned short* xk_base = xbf + ((size_t)b * S_) * D_ + h * DH_ + lg * 8;
  const unsigned short* vT_base = xnT + ((size_t)(b * D_ + h * DH_)) * S_;

  bf16x8 qkb[4];
#pragma unroll
  for (int c = 0; c < 4; c++)
    qkb[c] = *(const bf16x8*)(xk_base + (size_t)(c * 16 + lr) * D_);

  for (int kt = 0; kt < 16; kt++) {
    int k0 = kt * 64;
    bf16x8 pvb[2][2];
#pragma unroll
    for (int fs = 0; fs < 2; fs++)
#pragma unroll
      for (int kc = 0; kc < 2; kc++)
        pvb[fs][kc] = *(const bf16x8*)(vT_base + (size_t)(fs * 16 + lr) * S_ +
                                       k0 + kc * 32 + lg * 8);
    f32x4 s[4];
#pragma unroll
    for (int c = 0; c < 4; c++)
      s[c] = __builtin_amdgcn_mfma_f32_16x16x32_bf16(aq, qkb[c],
                (f32x4){0.f, 0.f, 0.f, 0.f}, 0, 0, 0);
    int ktn = kt < 15 ? kt + 1 : 15;
#pragma unroll
    for (int c = 0; c < 4; c++)
      qkb[c] = *(const bf16x8*)(xk_base + (size_t)(ktn * 64 + c * 16 + lr) * D_);
#pragma unroll
    for (int c = 0; c < 4; c++)
#pragma unroll
      for (int r = 0; r < 4; r++) {
        float p = __expf(s[c][r]);
        rsum[r] += p;
        P_lds[w][lg * 4 + r][c * 16 + lr] = f2bf(p);
      }
#pragma unroll
    for (int kc = 0; kc < 2; kc++) {
      bf16x8 pa = *(const bf16x8*)(&P_lds[w][lr][kc * 32 + lg * 8]);
#pragma unroll
      for (int fs = 0; fs < 2; fs++)
        accPV[fs] = __builtin_amdgcn_mfma_f32_16x16x32_bf16(pa, pvb[fs][kc],
                       accPV[fs], 0, 0, 0);
    }
  }

  float inv[4];
#pragma unroll
  for (int r = 0; r < 4; r++) {
    float v = rsum[r];
    v += __shfl_xor(v, 1, 64);
    v += __shfl_xor(v, 2, 64);
    v += __shfl_xor(v, 4, 64);
    v += __shfl_xor(v, 8, 64);
    inv[r] = 1.f / v;
  }
  // attention out -> LDS Aa (swizzled [16][256], BKB=512)
#pragma unroll
  for (int fs = 0; fs < 2; fs++)
#pragma unroll
    for (int r = 0; r < 4; r++) {
      float val = accPV[fs][r] * inv[r] * dvo[fs];
      int row = lg * 4 + r, col = h * DH_ + fs * 16 + lr;
      int byte = (row * 512 + col * 2) ^ ((row & 7) << 4);
      *(unsigned short*)((char*)Aa + byte) = f2bf(val);
    }
  __syncthreads();   // Aa visible; W panel 0 loads drained (implicit vmcnt 0)

  // ================= MLP: 12 panels, triple-buffered depth-2 pipeline ====
  int lr16 = lr;
  f32x4 acc[2];
  acc[0] = (f32x4){0.f, 0.f, 0.f, 0.f};
  acc[1] = (f32x4){0.f, 0.f, 0.f, 0.f};
  const unsigned short* Asrc = Aa;

  // prefetch panel 1
  stage_tile_swz<256, 64, 8>(Wl + 64, 256, Bp[1], w, lane);

  for (int p = 0; p < 12; ++p) {
    if (p < 10) {
      int pn = p + 2;
      stage_tile_swz<256, 64, 8>(Wl + (size_t)(pn >> 2) * 65536 + (pn & 3) * 64,
                                 256, Bp[pn % 3], w, lane);
    }
    int kk0 = (p & 3) * 64;
#pragma unroll
    for (int kk = 0; kk < 64; kk += 32) {
      bf16x8 a = lds_frag<512>(Asrc, lr16, (kk0 + kk) * 2 + lg * 16);
#pragma unroll
      for (int j = 0; j < 2; j++) {
        bf16x8 bfg = lds_frag<128>(Bp[p % 3], w * 32 + j * 16 + lr16, kk * 2 + lg * 16);
        acc[j] = __builtin_amdgcn_mfma_f32_16x16x32_bf16(a, bfg, acc[j], 0, 0, 0);
      }
    }
    if (p == 3 || p == 7) {
      const float* bias = (p == 3) ? b1 : b2;
      unsigned short* dst = (p == 3) ? Ab : Ab2;
#pragma unroll
      for (int j = 0; j < 2; j++) {
        int col = w * 32 + j * 16 + lr16;
        float bv = bias[col];
#pragma unroll
        for (int r = 0; r < 4; r++) {
          float v = acc[j][r] + bv;
          v = 0.5f * v * (1.f + erff(v * 0.70710678118654752f));
          int row = lg * 4 + r;
          int byte = (row * 512 + col * 2) ^ ((row & 7) << 4);
          *(unsigned short*)((char*)dst + byte) = f2bf(v);
        }
      }
      acc[0] = (f32x4){0.f, 0.f, 0.f, 0.f};
      acc[1] = (f32x4){0.f, 0.f, 0.f, 0.f};
      Asrc = (p == 3) ? Ab : Ab2;
      asm volatile("s_waitcnt lgkmcnt(0)" ::: "memory");  // Ab/Ab2 visible at barrier
    }
    // wait panel p+1's loads (oldest); leave p+2's in flight
    if (p < 10) asm volatile("s_waitcnt vmcnt(4)" ::: "memory");
    else        asm volatile("s_waitcnt vmcnt(0)" ::: "memory");
    __builtin_amdgcn_sched_barrier(0);
    __builtin_amdgcn_s_barrier();
  }

  // ---- final epilogue: bias3 + residual (+ next-layer LN dual emit) ----
#pragma unroll
  for (int j = 0; j < 2; j++) {
    int col = w * 32 + j * 16 + lr16;
    float bv = b3[col];
#pragma unroll
    for (int r = 0; r < 4; r++) {
      int row = lg * 4 + r; int grow = r0 + row;
      float v = acc[j][r] + bv + x[(size_t)grow * D_ + col];
      if constexpr (LAST) {
        actB[(size_t)grow * D_ + col] = f2bf(v);
      } else {
        x[(size_t)grow * D_ + col] = v;
        xf[row][col] = v;
      }
    }
  }

  if constexpr (!LAST) {
    __syncthreads();
#pragma unroll
    for (int rr = 0; rr < 2; rr++) {
      int row = w * 2 + rr; int grow = r0 + row;
      f32x4 v = *(const f32x4*)&xf[row][lane * 4];
      float s = v[0] + v[1] + v[2] + v[3];
      float ss = v[0]*v[0] + v[1]*v[1] + v[2]*v[2] + v[3]*v[3];
#pragma unroll
      for (int off = 1; off < 64; off <<= 1) {
        s  += __shfl_xor(s, off, 64);
        ss += __shfl_xor(ss, off, 64);
      }
      float mean = s * (1.f / D_);
      float var = ss * (1.f / D_) - mean * mean;
      float rinv = rsqrtf(var + 1e-5f);
      float4 g4 = *(const float4*)(lngN + lane * 4);
      float4 b4 = *(const float4*)(lnbN + lane * 4);
      ushort4 o;
      o.x = f2bf((v[0] - mean) * rinv * g4.x + b4.x);
      o.y = f2bf((v[1] - mean) * rinv * g4.y + b4.y);
      o.z = f2bf((v[2] - mean) * rinv * g4.z + b4.z);
      o.w = f2bf((v[3] - mean) * rinv * g4.w + b4.w);
      *(ushort4*)(xbfN + (size_t)grow * D_ + lane * 4) = o;
      if (lane == 0) { mrow[row] = mean; rrow[row] = rinv; }
    }
    __syncthreads();
    int d = tid & 255, half = tid >> 8;
    float gd = lngN[d], bd = lnbN[d];
    int bb = r0 >> 10, s0 = r0 & 1023;
    bf16x8 o8;
#pragma unroll
    for (int k = 0; k < 8; k++) {
      int srow = half * 8 + k;
      o8[k] = (short)f2bf((xf[srow][d] - mrow[srow]) * rrow[srow] * gd + bd);
    }
    *(bf16x8*)(xnTN + ((size_t)(bb * 256 + d)) * S_ + s0 + half * 8) = o8;
  }
}

// ---------------- logits GEMM: B-in-regs + LDS store-repack + full-line nt --------
// r17 counters: WRITE amplification 1.33x from 64B partial-line nt stores. Fix:
// acc -> Cs (dead Bs reused, swizzled) -> coalesced re-read -> nt stores where
// each half-wave covers one row's 512B contiguously (4 full 128B lines/instr).
// A-tile counted-vmcnt pipeline preserved (loads oldest; stores left in flight).
__global__ __launch_bounds__(512) void k_logits(
    const unsigned short* __restrict__ A,    // bf16 [4096][256]
    const float* __restrict__ logitW,        // f32 [256][32000]
    float* __restrict__ C) {
  __shared__ __align__(16) unsigned short Bs[128 * 256];    // 64 KB; reused as Cs
  __shared__ __align__(16) unsigned short As[2][64 * 256];  // 2 x 32 KB
  float* Cs = (float*)Bs;                     // [64][128] f32, swizzled rows

  int tid = threadIdx.x, lane = tid & 63, w = tid >> 6;
  int wm = w >> 2, wn = w & 3;               // 2 (row-groups) x 4 (col-groups)
  int lr = lane & 15, lg = lane >> 4;
  int bn0 = blockIdx.x * 128;

  // issue A tile 0 stage first (async; latency hides under the B-stage)
  stage_tile_swz<64, 256, 8>(A, 256, As[0], w, lane);

  // B-stage: transpose + convert logitW -> Bs [row=v][k] bf16, swizzled (BKB=512)
  {
    int c = tid & 127;          // col within slab (v - bn0)
    int kp = tid >> 7;          // 0..3
    for (int it = 0; it < 32; ++it) {
      int k = it * 8 + kp * 2;
      float f0 = logitW[(size_t)k * V_ + bn0 + c];
      float f1 = logitW[(size_t)(k + 1) * V_ + bn0 + c];
      unsigned pack = (unsigned)f2bf(f0) | ((unsigned)f2bf(f1) << 16);
      int byte = (c * 512 + k * 2) ^ ((c & 7) << 4);
      *(unsigned*)((char*)Bs + byte) = pack;
    }
  }
  __syncthreads();

  // hoist B fragments to registers
  bf16x8 breg[2][8];
#pragma unroll
  for (int j = 0; j < 2; j++)
#pragma unroll
    for (int ks = 0; ks < 8; ks++)
      breg[j][ks] = lds_frag<512>(Bs, wn * 32 + j * 16 + lr, ks * 64 + lg * 16);
  __syncthreads();   // all waves done reading Bs -> safe to reuse as Cs

  int crr = tid >> 5, ccc = tid & 31;        // repack-read coords

  for (int t = 0; t < 64; ++t) {
    int cur = t & 1;
    if (t < 63)
      stage_tile_swz<64, 256, 8>(A + (size_t)(t + 1) * 64 * 256, 256, As[cur ^ 1], w, lane);

    f32x4 acc[2][2];
#pragma unroll
    for (int i = 0; i < 2; i++)
#pragma unroll
      for (int j = 0; j < 2; j++) acc[i][j] = (f32x4){0.f, 0.f, 0.f, 0.f};

#pragma unroll
    for (int ks = 0; ks < 8; ks++) {
      bf16x8 af[2];
#pragma unroll
      for (int i = 0; i < 2; i++)
        af[i] = lds_frag<512>(As[cur], wm * 32 + i * 16 + lr, ks * 64 + lg * 16);
#pragma unroll
      for (int i = 0; i < 2; i++)
#pragma unroll
        for (int j = 0; j < 2; j++)
          acc[i][j] = __builtin_amdgcn_mfma_f32_16x16x32_bf16(breg[j][ks], af[i], acc[i][j], 0, 0, 0);
    }

    // acc -> Cs (swizzled): row = wm*32+i*16+lr, colbytes = (wn*32+j*16+lg*4)*4
#pragma unroll
    for (int i = 0; i < 2; i++)
#pragma unroll
      for (int j = 0; j < 2; j++) {
        int row = wm * 32 + i * 16 + lr;
        int byte = (row * 512 + (wn * 32 + j * 16 + lg * 4) * 4) ^ ((row & 7) << 4);
        *(f32x4*)((char*)Cs + byte) = acc[i][j];
      }
    asm volatile("s_waitcnt lgkmcnt(0)" ::: "memory");
    __builtin_amdgcn_sched_barrier(0);
    __builtin_amdgcn_s_barrier();

    // coalesced full-line nt stores: half-wave = one row's 512B
    int r0 = t * 64;
#pragma unroll
    for (int pss = 0; pss < 4; ++pss) {
      int row = pss * 16 + crr;
      int byte = (row * 512 + ccc * 16) ^ ((row & 7) << 4);
      f32x4 v = *(const f32x4*)((const char*)Cs + byte);
      __builtin_nontemporal_store(v, (f32x4*)(C + (size_t)(r0 + row) * V_ + bn0 + ccc * 4));
    }

    // wait own A loads(t+1) (oldest); leave the 4 stores in flight
    asm volatile("s_waitcnt vmcnt(4)" ::: "memory");
    __builtin_amdgcn_sched_barrier(0);
    __builtin_amdgcn_s_barrier();
  }
}

// ---------------- launch ----------------
extern "C" void kernel_launch(void* const* d_in, const int* in_sizes, int n_in,
                              void* d_out, int out_size, void* d_ws, size_t ws_size,
                              hipStream_t stream) {
  const int*   X      = (const int*)d_in[0];
  const float* emb    = (const float*)d_in[1];
  const float* WQ     = (const float*)d_in[2];
  const float* WK     = (const float*)d_in[3];
  const float* WV     = (const float*)d_in[4];
  const float* Om     = (const float*)d_in[5];
  const float* lng    = (const float*)d_in[6];
  const float* lnb    = (const float*)d_in[7];
  const float* w1     = (const float*)d_in[8];
  const float* b1     = (const float*)d_in[9];
  const float* w2     = (const float*)d_in[10];
  const float* b2     = (const float*)d_in[11];
  const float* w3     = (const float*)d_in[12];
  const float* b3     = (const float*)d_in[13];
  const float* logitW = (const float*)d_in[14];
  float* out = (float*)d_out;
  char* ws = (char*)d_ws;

  constexpr size_t MB = 1024u * 1024;
  float* x  = (float*)(ws);                                    // 4 MB
  unsigned short* xbf0 = (unsigned short*)(ws + 4 * MB);       // 2 MB
  unsigned short* xbf1 = (unsigned short*)(ws + 6 * MB);       // 2 MB
  unsigned short* xnT0 = (unsigned short*)(ws + 8 * MB);       // 2 MB
  unsigned short* xnT1 = (unsigned short*)(ws + 10 * MB);      // 2 MB
  unsigned short* actB = (unsigned short*)(ws + 12 * MB);      // 2 MB
  unsigned short* mlpW = (unsigned short*)(ws + 14 * MB);      // 1.5 MB

  // fused prep: embed+LN0 (256 blocks) + MLP weight tconv (192 blocks)
  k_prep<<<448, 512, 0, stream>>>(X, emb, lng, lnb, x, xbf0, xnT0, w1, w2, w3, mlpW);

  for (int l = 0; l < L_; l++) {
    const unsigned short* xbfI = (l & 1) ? xbf1 : xbf0;
    const unsigned short* xnTI = (l & 1) ? xnT1 : xnT0;
    unsigned short* xbfO = (l & 1) ? xbf0 : xbf1;
    unsigned short* xnTO = (l & 1) ? xnT0 : xnT1;
    if (l < L_ - 1) {
      k_layer<0><<<256, 512, 0, stream>>>(
          xbfI, xnTI, WQ, WK, WV, Om, mlpW + (size_t)(l * 3) * 65536,
          b1 + (size_t)l * D_, b2 + (size_t)l * D_, b3 + (size_t)l * D_, x,
          lng + (size_t)(l + 1) * D_, lnb + (size_t)(l + 1) * D_,
          xbfO, xnTO, nullptr, l);
    } else {
      k_layer<1><<<256, 512, 0, stream>>>(
          xbfI, xnTI, WQ, WK, WV, Om, mlpW + (size_t)(l * 3) * 65536,
          b1 + (size_t)l * D_, b2 + (size_t)l * D_, b3 + (size_t)l * D_, x,
          nullptr, nullptr, nullptr, nullptr, actB, l);
    }
  }

  // logits: store-repacked full-line nt writes
  k_logits<<<250, 512, 0, stream>>>(actB, logitW, out);
}

// Round 23
// 296.845 us; speedup vs baseline: 1.4570x; 1.0722x over previous
//
#include <hip/hip_runtime.h>
#include <hip/hip_bf16.h>
#include <cstdint>
#include <cstddef>

#define B_ 4
#define S_ 1024
#define V_ 32000
#define D_ 256
#define H_ 8
#define DH_ 32
#define L_ 4
#define MROWS (B_*S_)

typedef __attribute__((ext_vector_type(8))) short bf16x8;
typedef __attribute__((ext_vector_type(4))) float f32x4;

__device__ __forceinline__ unsigned short f2bf(float f) {
  union { float f; unsigned u; } c; c.f = f;
  unsigned u = c.u;
  u += 0x7fff + ((u >> 16) & 1);   // round-to-nearest-even
  return (unsigned short)(u >> 16);
}
__device__ __forceinline__ float bf2f(unsigned short u) {
  union { unsigned u; float f; } c; c.u = ((unsigned)u) << 16; return c.f;
}

// async global->LDS, 16B per lane; LDS dest is wave-uniform base + lane*16
__device__ __forceinline__ void gload16(const unsigned short* g, unsigned short* l) {
  __builtin_amdgcn_global_load_lds(
      (const __attribute__((address_space(1))) void*)g,
      (__attribute__((address_space(3))) void*)l, 16, 0, 0);
}

// ---- XOR-swizzled LDS tiles: lds[row][inner ^ ((row&7)<<4)] = g[row][inner]
template<int BM, int BK, int NW>
__device__ __forceinline__ void stage_tile_swz(const unsigned short* __restrict__ g, int ldg,
                                               unsigned short* lds, int wave, int lane) {
  constexpr int CH  = BM * BK * 2 / 1024;   // 1KB chunks
  constexpr int BKB = BK * 2;               // bytes per row
#pragma unroll
  for (int t = 0; t < CH / NW; ++t) {
    int c = wave + t * NW;
    int byte  = c * 1024 + lane * 16;
    int row   = byte / BKB;
    int inner = (byte % BKB) ^ ((row & 7) << 4);
    gload16(g + (size_t)row * ldg + (inner >> 1), lds + c * 512);
  }
}

// swizzled 16B fragment read: row-major [*][BKB/2] tile, kbytes multiple of 16
template<int BKB>
__device__ __forceinline__ bf16x8 lds_frag(const unsigned short* base, int row, int kbytes) {
  int b = (row * BKB + kbytes) ^ ((row & 7) << 4);
  return *(const bf16x8*)((const char*)base + b);
}

// ---------------- fused prep: embln (blocks 0..255) + MLP W tconv (256..447) ------
__global__ __launch_bounds__(512) void k_prep(
    const int* __restrict__ X, const float* __restrict__ emb,
    const float* __restrict__ lng, const float* __restrict__ lnb,
    float* __restrict__ x, unsigned short* __restrict__ xbf,
    unsigned short* __restrict__ xnT,
    const float* __restrict__ w1, const float* __restrict__ w2,
    const float* __restrict__ w3, unsigned short* __restrict__ mlpW) {
  int tid = threadIdx.x;
  if (blockIdx.x < 256) {
    __shared__ __align__(16) float xf[16][264];
    __shared__ float mrow[16], rrow[16];
    int r0 = blockIdx.x * 16;
    int w = tid >> 6, lane = tid & 63;
#pragma unroll
    for (int rr = 0; rr < 2; rr++) {
      int row = w * 2 + rr; int grow = r0 + row;
      int tok = X[grow];
      f32x4 v = *(const f32x4*)(emb + (size_t)tok * D_ + lane * 4);
      *(f32x4*)(x + (size_t)grow * D_ + lane * 4) = v;
      *(f32x4*)&xf[row][lane * 4] = v;
      float s = v[0] + v[1] + v[2] + v[3];
      float ss = v[0]*v[0] + v[1]*v[1] + v[2]*v[2] + v[3]*v[3];
#pragma unroll
      for (int off = 1; off < 64; off <<= 1) {
        s  += __shfl_xor(s, off, 64);
        ss += __shfl_xor(ss, off, 64);
      }
      float mean = s * (1.f / D_);
      float var = ss * (1.f / D_) - mean * mean;
      float rinv = rsqrtf(var + 1e-5f);
      float4 g4 = *(const float4*)(lng + lane * 4);
      float4 b4 = *(const float4*)(lnb + lane * 4);
      ushort4 o;
      o.x = f2bf((v[0] - mean) * rinv * g4.x + b4.x);
      o.y = f2bf((v[1] - mean) * rinv * g4.y + b4.y);
      o.z = f2bf((v[2] - mean) * rinv * g4.z + b4.z);
      o.w = f2bf((v[3] - mean) * rinv * g4.w + b4.w);
      *(ushort4*)(xbf + (size_t)grow * D_ + lane * 4) = o;
      if (lane == 0) { mrow[row] = mean; rrow[row] = rinv; }
    }
    __syncthreads();
    int d = tid & 255, half = tid >> 8;
    float gd = lng[d], bd = lnb[d];
    int bb = r0 >> 10, s0 = r0 & 1023;
    bf16x8 o8;
#pragma unroll
    for (int k = 0; k < 8; k++) {
      int srow = half * 8 + k;
      o8[k] = (short)f2bf((xf[srow][d] - mrow[srow]) * rrow[srow] * gd + bd);
    }
    *(bf16x8*)(xnT + ((size_t)(bb * 256 + d)) * S_ + s0 + half * 8) = o8;
  } else {
    __shared__ float tile[64][65];
    int idx = blockIdx.x - 256;               // 0..191
    int z = idx >> 4;                         // 0..11  (l*3+mm)
    int rem = idx & 15;
    int r0 = (rem >> 2) * 64, c0 = (rem & 3) * 64;
    int l = z / 3, mm = z % 3;
    const float* in = (mm == 0 ? w1 : mm == 1 ? w2 : w3) + (size_t)l * 65536;
    unsigned short* out = mlpW + (size_t)z * 65536;
    int t = tid & 255;
    bool act = tid < 256;
    if (act) {
#pragma unroll
      for (int i = 0; i < 16; i++) {
        int id2 = i * 256 + t;
        int lr = id2 >> 6, lc = id2 & 63;
        tile[lr][lc] = in[(size_t)(r0 + lr) * 256 + c0 + lc];
      }
    }
    __syncthreads();
    if (act) {
#pragma unroll
      for (int i = 0; i < 16; i++) {
        int id2 = i * 256 + t;
        int lr = id2 >> 6, lc = id2 & 63;
        out[(size_t)(c0 + lr) * 256 + r0 + lc] = f2bf(tile[lc][lr]);
      }
    }
  }
}

// ---------------- fused layer: attn + 3-GEMM MLP with depth-2 panel pipeline ------
template<int LAST>
__global__ __launch_bounds__(512) void k_layer(
    const unsigned short* __restrict__ xbf,   // layer input  [4096][256] bf16
    const unsigned short* __restrict__ xnT,   // layer input  [4][256][1024] bf16
    const float* __restrict__ WQ, const float* __restrict__ WK,
    const float* __restrict__ WV, const float* __restrict__ Om,
    const unsigned short* __restrict__ Wl,    // 3 x [256][256] bf16 (this layer)
    const float* __restrict__ b1, const float* __restrict__ b2, const float* __restrict__ b3,
    float* __restrict__ x,                    // residual f32
    const float* __restrict__ lngN, const float* __restrict__ lnbN,
    unsigned short* __restrict__ xbfN, unsigned short* __restrict__ xnTN,  // outputs (!LAST)
    unsigned short* __restrict__ actB,        // output (LAST)
    int layer) {
  __shared__ __align__(16) unsigned short P_lds[8][16][72];
  __shared__ __align__(16) unsigned short Aa[16 * 256];
  __shared__ __align__(16) unsigned short Ab[16 * 256];
  __shared__ __align__(16) unsigned short Ab2[16 * 256];
  __shared__ __align__(16) unsigned short Bp[3][256 * 64];
  __shared__ __align__(16) float xf[16][264];
  __shared__ float mrow[16], rrow[16];

  int b = blockIdx.x >> 6;
  int q0 = (blockIdx.x & 63) << 4;
  int r0 = blockIdx.x * 16;                  // == b*S + q0
  int tid = threadIdx.x;
  int w = tid >> 6, lane = tid & 63;
  int lr = lane & 15, lg = lane >> 4;
  int h = w;

  // prefetch MLP W panel 0 (drained at the post-attention barrier)
  stage_tile_swz<256, 64, 8>(Wl, 256, Bp[0], w, lane);

  // ================= attention =================
  const float scale = 0.17677669529663687f;  // 1/sqrt(32)
  bf16x8 aq;
  {
    bf16x8 xq = *(const bf16x8*)(xbf + ((size_t)(b * S_ + q0 + lr)) * D_ + h * DH_ + lg * 8);
#pragma unroll
    for (int j = 0; j < 8; j++) {
      int dj = lg * 8 + j;
      float wq = WQ[((size_t)(layer * H_ + h)) * 1024 + dj * 33];
      float wk = WK[((size_t)(layer * H_ + h)) * 1024 + dj * 33];
      aq[j] = (short)f2bf(bf2f((unsigned short)xq[j]) * wq * wk * scale);
    }
  }
  float dvo[2];
#pragma unroll
  for (int fs = 0; fs < 2; fs++) {
    int fh = fs * 16 + lr;
    int fc = h * DH_ + fh;
    dvo[fs] = WV[((size_t)(layer * H_ + h)) * 1024 + fh * 33] *
              Om[(size_t)layer * 65536 + (size_t)fc * 257];
  }

  f32x4 accPV[2];
  accPV[0] = (f32x4){0.f, 0.f, 0.f, 0.f};
  accPV[1] = (f32x4){0.f, 0.f, 0.f, 0.f};
  float rsum[4] = {0.f, 0.f, 0.f, 0.f};

  const unsigned short* xk_base = xbf + ((size_t)b * S_) * D_ + h * DH_ + lg * 8;
  const unsigned short* vT_base = xnT + ((size_t)(b * D_ + h * DH_)) * S_;

  bf16x8 qkb[4];
#pragma unroll
  for (int c = 0; c < 4; c++)
    qkb[c] = *(const bf16x8*)(xk_base + (size_t)(c * 16 + lr) * D_);

  for (int kt = 0; kt < 16; kt++) {
    int k0 = kt * 64;
    bf16x8 pvb[2][2];
#pragma unroll
    for (int fs = 0; fs < 2; fs++)
#pragma unroll
      for (int kc = 0; kc < 2; kc++)
        pvb[fs][kc] = *(const bf16x8*)(vT_base + (size_t)(fs * 16 + lr) * S_ +
                                       k0 + kc * 32 + lg * 8);
    f32x4 s[4];
#pragma unroll
    for (int c = 0; c < 4; c++)
      s[c] = __builtin_amdgcn_mfma_f32_16x16x32_bf16(aq, qkb[c],
                (f32x4){0.f, 0.f, 0.f, 0.f}, 0, 0, 0);
    int ktn = kt < 15 ? kt + 1 : 15;
#pragma unroll
    for (int c = 0; c < 4; c++)
      qkb[c] = *(const bf16x8*)(xk_base + (size_t)(ktn * 64 + c * 16 + lr) * D_);
#pragma unroll
    for (int c = 0; c < 4; c++)
#pragma unroll
      for (int r = 0; r < 4; r++) {
        float p = __expf(s[c][r]);
        rsum[r] += p;
        P_lds[w][lg * 4 + r][c * 16 + lr] = f2bf(p);
      }
#pragma unroll
    for (int kc = 0; kc < 2; kc++) {
      bf16x8 pa = *(const bf16x8*)(&P_lds[w][lr][kc * 32 + lg * 8]);
#pragma unroll
      for (int fs = 0; fs < 2; fs++)
        accPV[fs] = __builtin_amdgcn_mfma_f32_16x16x32_bf16(pa, pvb[fs][kc],
                       accPV[fs], 0, 0, 0);
    }
  }

  float inv[4];
#pragma unroll
  for (int r = 0; r < 4; r++) {
    float v = rsum[r];
    v += __shfl_xor(v, 1, 64);
    v += __shfl_xor(v, 2, 64);
    v += __shfl_xor(v, 4, 64);
    v += __shfl_xor(v, 8, 64);
    inv[r] = 1.f / v;
  }
  // attention out -> LDS Aa (swizzled [16][256], BKB=512)
#pragma unroll
  for (int fs = 0; fs < 2; fs++)
#pragma unroll
    for (int r = 0; r < 4; r++) {
      float val = accPV[fs][r] * inv[r] * dvo[fs];
      int row = lg * 4 + r, col = h * DH_ + fs * 16 + lr;
      int byte = (row * 512 + col * 2) ^ ((row & 7) << 4);
      *(unsigned short*)((char*)Aa + byte) = f2bf(val);
    }
  __syncthreads();   // Aa visible; W panel 0 loads drained (implicit vmcnt 0)

  // ================= MLP: 12 panels, triple-buffered depth-2 pipeline ====
  int lr16 = lr;
  f32x4 acc[2];
  acc[0] = (f32x4){0.f, 0.f, 0.f, 0.f};
  acc[1] = (f32x4){0.f, 0.f, 0.f, 0.f};
  const unsigned short* Asrc = Aa;

  // prefetch panel 1
  stage_tile_swz<256, 64, 8>(Wl + 64, 256, Bp[1], w, lane);

  for (int p = 0; p < 12; ++p) {
    if (p < 10) {
      int pn = p + 2;
      stage_tile_swz<256, 64, 8>(Wl + (size_t)(pn >> 2) * 65536 + (pn & 3) * 64,
                                 256, Bp[pn % 3], w, lane);
    }
    int kk0 = (p & 3) * 64;
#pragma unroll
    for (int kk = 0; kk < 64; kk += 32) {
      bf16x8 a = lds_frag<512>(Asrc, lr16, (kk0 + kk) * 2 + lg * 16);
#pragma unroll
      for (int j = 0; j < 2; j++) {
        bf16x8 bfg = lds_frag<128>(Bp[p % 3], w * 32 + j * 16 + lr16, kk * 2 + lg * 16);
        acc[j] = __builtin_amdgcn_mfma_f32_16x16x32_bf16(a, bfg, acc[j], 0, 0, 0);
      }
    }
    if (p == 3 || p == 7) {
      const float* bias = (p == 3) ? b1 : b2;
      unsigned short* dst = (p == 3) ? Ab : Ab2;
#pragma unroll
      for (int j = 0; j < 2; j++) {
        int col = w * 32 + j * 16 + lr16;
        float bv = bias[col];
#pragma unroll
        for (int r = 0; r < 4; r++) {
          float v = acc[j][r] + bv;
          v = 0.5f * v * (1.f + erff(v * 0.70710678118654752f));
          int row = lg * 4 + r;
          int byte = (row * 512 + col * 2) ^ ((row & 7) << 4);
          *(unsigned short*)((char*)dst + byte) = f2bf(v);
        }
      }
      acc[0] = (f32x4){0.f, 0.f, 0.f, 0.f};
      acc[1] = (f32x4){0.f, 0.f, 0.f, 0.f};
      Asrc = (p == 3) ? Ab : Ab2;
      asm volatile("s_waitcnt lgkmcnt(0)" ::: "memory");  // Ab/Ab2 visible at barrier
    }
    // wait panel p+1's loads (oldest); leave p+2's in flight
    if (p < 10) asm volatile("s_waitcnt vmcnt(4)" ::: "memory");
    else        asm volatile("s_waitcnt vmcnt(0)" ::: "memory");
    __builtin_amdgcn_sched_barrier(0);
    __builtin_amdgcn_s_barrier();
  }

  // ---- final epilogue: bias3 + residual (+ next-layer LN dual emit) ----
#pragma unroll
  for (int j = 0; j < 2; j++) {
    int col = w * 32 + j * 16 + lr16;
    float bv = b3[col];
#pragma unroll
    for (int r = 0; r < 4; r++) {
      int row = lg * 4 + r; int grow = r0 + row;
      float v = acc[j][r] + bv + x[(size_t)grow * D_ + col];
      if constexpr (LAST) {
        actB[(size_t)grow * D_ + col] = f2bf(v);
      } else {
        x[(size_t)grow * D_ + col] = v;
        xf[row][col] = v;
      }
    }
  }

  if constexpr (!LAST) {
    __syncthreads();
#pragma unroll
    for (int rr = 0; rr < 2; rr++) {
      int row = w * 2 + rr; int grow = r0 + row;
      f32x4 v = *(const f32x4*)&xf[row][lane * 4];
      float s = v[0] + v[1] + v[2] + v[3];
      float ss = v[0]*v[0] + v[1]*v[1] + v[2]*v[2] + v[3]*v[3];
#pragma unroll
      for (int off = 1; off < 64; off <<= 1) {
        s  += __shfl_xor(s, off, 64);
        ss += __shfl_xor(ss, off, 64);
      }
      float mean = s * (1.f / D_);
      float var = ss * (1.f / D_) - mean * mean;
      float rinv = rsqrtf(var + 1e-5f);
      float4 g4 = *(const float4*)(lngN + lane * 4);
      float4 b4 = *(const float4*)(lnbN + lane * 4);
      ushort4 o;
      o.x = f2bf((v[0] - mean) * rinv * g4.x + b4.x);
      o.y = f2bf((v[1] - mean) * rinv * g4.y + b4.y);
      o.z = f2bf((v[2] - mean) * rinv * g4.z + b4.z);
      o.w = f2bf((v[3] - mean) * rinv * g4.w + b4.w);
      *(ushort4*)(xbfN + (size_t)grow * D_ + lane * 4) = o;
      if (lane == 0) { mrow[row] = mean; rrow[row] = rinv; }
    }
    __syncthreads();
    int d = tid & 255, half = tid >> 8;
    float gd = lngN[d], bd = lnbN[d];
    int bb = r0 >> 10, s0 = r0 & 1023;
    bf16x8 o8;
#pragma unroll
    for (int k = 0; k < 8; k++) {
      int srow = half * 8 + k;
      o8[k] = (short)f2bf((xf[srow][d] - mrow[srow]) * rrow[srow] * gd + bd);
    }
    *(bf16x8*)(xnTN + ((size_t)(bb * 256 + d)) * S_ + s0 + half * 8) = o8;
  }
}

// ---------------- logits GEMM: B-in-regs + double-buffered Cs repack, 1 barrier ---
// r22 banked the full-line nt store repack; this round merges the two per-iter
// barriers into ONE via Cs double-buffering (Cs = 2 x 32KB inside dead Bs).
// Per iter: stage As(t+1) | MFMA As[cur] | acc->Cs[b] | vmcnt(4)+lgkmcnt(0) |
// s_barrier | read Cs[b] | nt-store. Safety: As reuse and Cs[b^1] rewrites are
// separated from their readers by the single barrier (program order).
__global__ __launch_bounds__(512) void k_logits(
    const unsigned short* __restrict__ A,    // bf16 [4096][256]
    const float* __restrict__ logitW,        // f32 [256][32000]
    float* __restrict__ C) {
  __shared__ __align__(16) unsigned short Bs[128 * 256];    // 64 KB; reused as Cs[2]
  __shared__ __align__(16) unsigned short As[2][64 * 256];  // 2 x 32 KB

  int tid = threadIdx.x, lane = tid & 63, w = tid >> 6;
  int wm = w >> 2, wn = w & 3;               // 2 (row-groups) x 4 (col-groups)
  int lr = lane & 15, lg = lane >> 4;
  int bn0 = blockIdx.x * 128;

  // issue A tile 0 stage first (async; latency hides under the B-stage)
  stage_tile_swz<64, 256, 8>(A, 256, As[0], w, lane);

  // B-stage: transpose + convert logitW -> Bs [row=v][k] bf16, swizzled (BKB=512)
  {
    int c = tid & 127;          // col within slab (v - bn0)
    int kp = tid >> 7;          // 0..3
    for (int it = 0; it < 32; ++it) {
      int k = it * 8 + kp * 2;
      float f0 = logitW[(size_t)k * V_ + bn0 + c];
      float f1 = logitW[(size_t)(k + 1) * V_ + bn0 + c];
      unsigned pack = (unsigned)f2bf(f0) | ((unsigned)f2bf(f1) << 16);
      int byte = (c * 512 + k * 2) ^ ((c & 7) << 4);
      *(unsigned*)((char*)Bs + byte) = pack;
    }
  }
  __syncthreads();

  // hoist B fragments to registers
  bf16x8 breg[2][8];
#pragma unroll
  for (int j = 0; j < 2; j++)
#pragma unroll
    for (int ks = 0; ks < 8; ks++)
      breg[j][ks] = lds_frag<512>(Bs, wn * 32 + j * 16 + lr, ks * 64 + lg * 16);
  __syncthreads();   // all waves done reading Bs -> safe to reuse as Cs

  int crr = tid >> 5, ccc = tid & 31;        // repack-read coords

  for (int t = 0; t < 64; ++t) {
    int cur = t & 1;
    char* Cs = (char*)Bs + (t & 1) * 32768;  // double-buffered 32KB halves
    if (t < 63)
      stage_tile_swz<64, 256, 8>(A + (size_t)(t + 1) * 64 * 256, 256, As[cur ^ 1], w, lane);

    f32x4 acc[2][2];
#pragma unroll
    for (int i = 0; i < 2; i++)
#pragma unroll
      for (int j = 0; j < 2; j++) acc[i][j] = (f32x4){0.f, 0.f, 0.f, 0.f};

#pragma unroll
    for (int ks = 0; ks < 8; ks++) {
      bf16x8 af[2];
#pragma unroll
      for (int i = 0; i < 2; i++)
        af[i] = lds_frag<512>(As[cur], wm * 32 + i * 16 + lr, ks * 64 + lg * 16);
#pragma unroll
      for (int i = 0; i < 2; i++)
#pragma unroll
        for (int j = 0; j < 2; j++)
          acc[i][j] = __builtin_amdgcn_mfma_f32_16x16x32_bf16(breg[j][ks], af[i], acc[i][j], 0, 0, 0);
    }

    // acc -> Cs (swizzled): row = wm*32+i*16+lr, colbytes = (wn*32+j*16+lg*4)*4
#pragma unroll
    for (int i = 0; i < 2; i++)
#pragma unroll
      for (int j = 0; j < 2; j++) {
        int row = wm * 32 + i * 16 + lr;
        int byte = (row * 512 + (wn * 32 + j * 16 + lg * 4) * 4) ^ ((row & 7) << 4);
        *(f32x4*)(Cs + byte) = acc[i][j];
      }

    // single barrier: As(t+1) landed (vmcnt 4: loads are oldest, stores stay
    // in flight), Cs writes visible (lgkmcnt 0)
    asm volatile("s_waitcnt vmcnt(4) lgkmcnt(0)" ::: "memory");
    __builtin_amdgcn_sched_barrier(0);
    __builtin_amdgcn_s_barrier();

    // coalesced full-line nt stores: half-wave = one row's 512B
    int r0 = t * 64;
#pragma unroll
    for (int pss = 0; pss < 4; ++pss) {
      int row = pss * 16 + crr;
      int byte = (row * 512 + ccc * 16) ^ ((row & 7) << 4);
      f32x4 v = *(const f32x4*)(Cs + byte);
      __builtin_nontemporal_store(v, (f32x4*)(C + (size_t)(r0 + row) * V_ + bn0 + ccc * 4));
    }
  }
}

// ---------------- launch ----------------
extern "C" void kernel_launch(void* const* d_in, const int* in_sizes, int n_in,
                              void* d_out, int out_size, void* d_ws, size_t ws_size,
                              hipStream_t stream) {
  const int*   X      = (const int*)d_in[0];
  const float* emb    = (const float*)d_in[1];
  const float* WQ     = (const float*)d_in[2];
  const float* WK     = (const float*)d_in[3];
  const float* WV     = (const float*)d_in[4];
  const float* Om     = (const float*)d_in[5];
  const float* lng    = (const float*)d_in[6];
  const float* lnb    = (const float*)d_in[7];
  const float* w1     = (const float*)d_in[8];
  const float* b1     = (const float*)d_in[9];
  const float* w2     = (const float*)d_in[10];
  const float* b2     = (const float*)d_in[11];
  const float* w3     = (const float*)d_in[12];
  const float* b3     = (const float*)d_in[13];
  const float* logitW = (const float*)d_in[14];
  float* out = (float*)d_out;
  char* ws = (char*)d_ws;

  constexpr size_t MB = 1024u * 1024;
  float* x  = (float*)(ws);                                    // 4 MB
  unsigned short* xbf0 = (unsigned short*)(ws + 4 * MB);       // 2 MB
  unsigned short* xbf1 = (unsigned short*)(ws + 6 * MB);       // 2 MB
  unsigned short* xnT0 = (unsigned short*)(ws + 8 * MB);       // 2 MB
  unsigned short* xnT1 = (unsigned short*)(ws + 10 * MB);      // 2 MB
  unsigned short* actB = (unsigned short*)(ws + 12 * MB);      // 2 MB
  unsigned short* mlpW = (unsigned short*)(ws + 14 * MB);      // 1.5 MB

  // fused prep: embed+LN0 (256 blocks) + MLP weight tconv (192 blocks)
  k_prep<<<448, 512, 0, stream>>>(X, emb, lng, lnb, x, xbf0, xnT0, w1, w2, w3, mlpW);

  for (int l = 0; l < L_; l++) {
    const unsigned short* xbfI = (l & 1) ? xbf1 : xbf0;
    const unsigned short* xnTI = (l & 1) ? xnT1 : xnT0;
    unsigned short* xbfO = (l & 1) ? xbf0 : xbf1;
    unsigned short* xnTO = (l & 1) ? xnT0 : xnT1;
    if (l < L_ - 1) {
      k_layer<0><<<256, 512, 0, stream>>>(
          xbfI, xnTI, WQ, WK, WV, Om, mlpW + (size_t)(l * 3) * 65536,
          b1 + (size_t)l * D_, b2 + (size_t)l * D_, b3 + (size_t)l * D_, x,
          lng + (size_t)(l + 1) * D_, lnb + (size_t)(l + 1) * D_,
          xbfO, xnTO, nullptr, l);
    } else {
      k_layer<1><<<256, 512, 0, stream>>>(
          xbfI, xnTI, WQ, WK, WV, Om, mlpW + (size_t)(l * 3) * 65536,
          b1 + (size_t)l * D_, b2 + (size_t)l * D_, b3 + (size_t)l * D_, x,
          nullptr, nullptr, nullptr, nullptr, actB, l);
    }
  }

  // logits: double-buffered Cs repack, one barrier/iter
  k_logits<<<250, 512, 0, stream>>>(actB, logitW, out);
}

// Round 24
// 290.722 us; speedup vs baseline: 1.4877x; 1.0211x over previous
//
#include <hip/hip_runtime.h>
#include <hip/hip_bf16.h>
#include <cstdint>
#include <cstddef>

#define B_ 4
#define S_ 1024
#define V_ 32000
#define D_ 256
#define H_ 8
#define DH_ 32
#define L_ 4
#define MROWS (B_*S_)

typedef __attribute__((ext_vector_type(8))) short bf16x8;
typedef __attribute__((ext_vector_type(4))) float f32x4;

__device__ __forceinline__ unsigned short f2bf(float f) {
  union { float f; unsigned u; } c; c.f = f;
  unsigned u = c.u;
  u += 0x7fff + ((u >> 16) & 1);   // round-to-nearest-even
  return (unsigned short)(u >> 16);
}
__device__ __forceinline__ float bf2f(unsigned short u) {
  union { unsigned u; float f; } c; c.u = ((unsigned)u) << 16; return c.f;
}

// async global->LDS, 16B per lane; LDS dest is wave-uniform base + lane*16
__device__ __forceinline__ void gload16(const unsigned short* g, unsigned short* l) {
  __builtin_amdgcn_global_load_lds(
      (const __attribute__((address_space(1))) void*)g,
      (__attribute__((address_space(3))) void*)l, 16, 0, 0);
}

// ---- XOR-swizzled LDS tiles: lds[row][inner ^ ((row&7)<<4)] = g[row][inner]
template<int BM, int BK, int NW>
__device__ __forceinline__ void stage_tile_swz(const unsigned short* __restrict__ g, int ldg,
                                               unsigned short* lds, int wave, int lane) {
  constexpr int CH  = BM * BK * 2 / 1024;   // 1KB chunks
  constexpr int BKB = BK * 2;               // bytes per row
#pragma unroll
  for (int t = 0; t < CH / NW; ++t) {
    int c = wave + t * NW;
    int byte  = c * 1024 + lane * 16;
    int row   = byte / BKB;
    int inner = (byte % BKB) ^ ((row & 7) << 4);
    gload16(g + (size_t)row * ldg + (inner >> 1), lds + c * 512);
  }
}

// swizzled 16B fragment read: row-major [*][BKB/2] tile, kbytes multiple of 16
template<int BKB>
__device__ __forceinline__ bf16x8 lds_frag(const unsigned short* base, int row, int kbytes) {
  int b = (row * BKB + kbytes) ^ ((row & 7) << 4);
  return *(const bf16x8*)((const char*)base + b);
}

// ---------------- fused prep: embln (blocks 0..255) + MLP W tconv (256..447) ------
__global__ __launch_bounds__(512) void k_prep(
    const int* __restrict__ X, const float* __restrict__ emb,
    const float* __restrict__ lng, const float* __restrict__ lnb,
    float* __restrict__ x, unsigned short* __restrict__ xbf,
    unsigned short* __restrict__ xnT,
    const float* __restrict__ w1, const float* __restrict__ w2,
    const float* __restrict__ w3, unsigned short* __restrict__ mlpW) {
  int tid = threadIdx.x;
  if (blockIdx.x < 256) {
    __shared__ __align__(16) float xf[16][264];
    __shared__ float mrow[16], rrow[16];
    int r0 = blockIdx.x * 16;
    int w = tid >> 6, lane = tid & 63;
#pragma unroll
    for (int rr = 0; rr < 2; rr++) {
      int row = w * 2 + rr; int grow = r0 + row;
      int tok = X[grow];
      f32x4 v = *(const f32x4*)(emb + (size_t)tok * D_ + lane * 4);
      *(f32x4*)(x + (size_t)grow * D_ + lane * 4) = v;
      *(f32x4*)&xf[row][lane * 4] = v;
      float s = v[0] + v[1] + v[2] + v[3];
      float ss = v[0]*v[0] + v[1]*v[1] + v[2]*v[2] + v[3]*v[3];
#pragma unroll
      for (int off = 1; off < 64; off <<= 1) {
        s  += __shfl_xor(s, off, 64);
        ss += __shfl_xor(ss, off, 64);
      }
      float mean = s * (1.f / D_);
      float var = ss * (1.f / D_) - mean * mean;
      float rinv = rsqrtf(var + 1e-5f);
      float4 g4 = *(const float4*)(lng + lane * 4);
      float4 b4 = *(const float4*)(lnb + lane * 4);
      ushort4 o;
      o.x = f2bf((v[0] - mean) * rinv * g4.x + b4.x);
      o.y = f2bf((v[1] - mean) * rinv * g4.y + b4.y);
      o.z = f2bf((v[2] - mean) * rinv * g4.z + b4.z);
      o.w = f2bf((v[3] - mean) * rinv * g4.w + b4.w);
      *(ushort4*)(xbf + (size_t)grow * D_ + lane * 4) = o;
      if (lane == 0) { mrow[row] = mean; rrow[row] = rinv; }
    }
    __syncthreads();
    int d = tid & 255, half = tid >> 8;
    float gd = lng[d], bd = lnb[d];
    int bb = r0 >> 10, s0 = r0 & 1023;
    bf16x8 o8;
#pragma unroll
    for (int k = 0; k < 8; k++) {
      int srow = half * 8 + k;
      o8[k] = (short)f2bf((xf[srow][d] - mrow[srow]) * rrow[srow] * gd + bd);
    }
    *(bf16x8*)(xnT + ((size_t)(bb * 256 + d)) * S_ + s0 + half * 8) = o8;
  } else {
    __shared__ float tile[64][65];
    int idx = blockIdx.x - 256;               // 0..191
    int z = idx >> 4;                         // 0..11  (l*3+mm)
    int rem = idx & 15;
    int r0 = (rem >> 2) * 64, c0 = (rem & 3) * 64;
    int l = z / 3, mm = z % 3;
    const float* in = (mm == 0 ? w1 : mm == 1 ? w2 : w3) + (size_t)l * 65536;
    unsigned short* out = mlpW + (size_t)z * 65536;
    int t = tid & 255;
    bool act = tid < 256;
    if (act) {
#pragma unroll
      for (int i = 0; i < 16; i++) {
        int id2 = i * 256 + t;
        int lr = id2 >> 6, lc = id2 & 63;
        tile[lr][lc] = in[(size_t)(r0 + lr) * 256 + c0 + lc];
      }
    }
    __syncthreads();
    if (act) {
#pragma unroll
      for (int i = 0; i < 16; i++) {
        int id2 = i * 256 + t;
        int lr = id2 >> 6, lc = id2 & 63;
        out[(size_t)(c0 + lr) * 256 + r0 + lc] = f2bf(tile[lc][lr]);
      }
    }
  }
}

// ---------------- fused layer: attn + MLP with per-wave self-timed panel pipeline -
// Wave w only reads rows w*32..w*32+31 of each W panel -> each wave stages its
// OWN 4KB slice and self-times with counted vmcnt; NO cross-wave barriers in the
// panel loop. Barriers remain only at real sharing points: Aa (post-attn),
// Ab / Ab2 handoffs (lgkmcnt(0)+raw s_barrier -- no vmcnt drain, pipeline lives).
template<int LAST>
__global__ __launch_bounds__(512) void k_layer(
    const unsigned short* __restrict__ xbf,   // layer input  [4096][256] bf16
    const unsigned short* __restrict__ xnT,   // layer input  [4][256][1024] bf16
    const float* __restrict__ WQ, const float* __restrict__ WK,
    const float* __restrict__ WV, const float* __restrict__ Om,
    const unsigned short* __restrict__ Wl,    // 3 x [256][256] bf16 (this layer)
    const float* __restrict__ b1, const float* __restrict__ b2, const float* __restrict__ b3,
    float* __restrict__ x,                    // residual f32
    const float* __restrict__ lngN, const float* __restrict__ lnbN,
    unsigned short* __restrict__ xbfN, unsigned short* __restrict__ xnTN,  // outputs (!LAST)
    unsigned short* __restrict__ actB,        // output (LAST)
    int layer) {
  __shared__ __align__(16) unsigned short P_lds[8][16][72];
  __shared__ __align__(16) unsigned short Aa[16 * 256];
  __shared__ __align__(16) unsigned short Ab[16 * 256];
  __shared__ __align__(16) unsigned short Ab2[16 * 256];
  __shared__ __align__(16) unsigned short Bp[3][256 * 64];
  __shared__ __align__(16) float xf[16][264];
  __shared__ float mrow[16], rrow[16];

  int b = blockIdx.x >> 6;
  int q0 = (blockIdx.x & 63) << 4;
  int r0 = blockIdx.x * 16;                  // == b*S + q0
  int tid = threadIdx.x;
  int w = tid >> 6, lane = tid & 63;
  int lr = lane & 15, lg = lane >> 4;
  int h = w;

  // ================= attention =================
  const float scale = 0.17677669529663687f;  // 1/sqrt(32)
  bf16x8 aq;
  {
    bf16x8 xq = *(const bf16x8*)(xbf + ((size_t)(b * S_ + q0 + lr)) * D_ + h * DH_ + lg * 8);
#pragma unroll
    for (int j = 0; j < 8; j++) {
      int dj = lg * 8 + j;
      float wq = WQ[((size_t)(layer * H_ + h)) * 1024 + dj * 33];
      float wk = WK[((size_t)(layer * H_ + h)) * 1024 + dj * 33];
      aq[j] = (short)f2bf(bf2f((unsigned short)xq[j]) * wq * wk * scale);
    }
  }
  float dvo[2];
#pragma unroll
  for (int fs = 0; fs < 2; fs++) {
    int fh = fs * 16 + lr;
    int fc = h * DH_ + fh;
    dvo[fs] = WV[((size_t)(layer * H_ + h)) * 1024 + fh * 33] *
              Om[(size_t)layer * 65536 + (size_t)fc * 257];
  }
  // hoist MLP biases to registers (keeps the panel loop free of VMEM ops)
  float bv1[2], bv2[2], bv3[2];
#pragma unroll
  for (int j = 0; j < 2; j++) {
    int col = w * 32 + j * 16 + lr;
    bv1[j] = b1[col]; bv2[j] = b2[col]; bv3[j] = b3[col];
  }

  f32x4 accPV[2];
  accPV[0] = (f32x4){0.f, 0.f, 0.f, 0.f};
  accPV[1] = (f32x4){0.f, 0.f, 0.f, 0.f};
  float rsum[4] = {0.f, 0.f, 0.f, 0.f};

  const unsigned short* xk_base = xbf + ((size_t)b * S_) * D_ + h * DH_ + lg * 8;
  const unsigned short* vT_base = xnT + ((size_t)(b * D_ + h * DH_)) * S_;

  bf16x8 qkb[4];
#pragma unroll
  for (int c = 0; c < 4; c++)
    qkb[c] = *(const bf16x8*)(xk_base + (size_t)(c * 16 + lr) * D_);

  for (int kt = 0; kt < 16; kt++) {
    int k0 = kt * 64;
    bf16x8 pvb[2][2];
#pragma unroll
    for (int fs = 0; fs < 2; fs++)
#pragma unroll
      for (int kc = 0; kc < 2; kc++)
        pvb[fs][kc] = *(const bf16x8*)(vT_base + (size_t)(fs * 16 + lr) * S_ +
                                       k0 + kc * 32 + lg * 8);
    f32x4 s[4];
#pragma unroll
    for (int c = 0; c < 4; c++)
      s[c] = __builtin_amdgcn_mfma_f32_16x16x32_bf16(aq, qkb[c],
                (f32x4){0.f, 0.f, 0.f, 0.f}, 0, 0, 0);
    int ktn = kt < 15 ? kt + 1 : 15;
#pragma unroll
    for (int c = 0; c < 4; c++)
      qkb[c] = *(const bf16x8*)(xk_base + (size_t)(ktn * 64 + c * 16 + lr) * D_);
#pragma unroll
    for (int c = 0; c < 4; c++)
#pragma unroll
      for (int r = 0; r < 4; r++) {
        float p = __expf(s[c][r]);
        rsum[r] += p;
        P_lds[w][lg * 4 + r][c * 16 + lr] = f2bf(p);
      }
#pragma unroll
    for (int kc = 0; kc < 2; kc++) {
      bf16x8 pa = *(const bf16x8*)(&P_lds[w][lr][kc * 32 + lg * 8]);
#pragma unroll
      for (int fs = 0; fs < 2; fs++)
        accPV[fs] = __builtin_amdgcn_mfma_f32_16x16x32_bf16(pa, pvb[fs][kc],
                       accPV[fs], 0, 0, 0);
    }
  }

  float inv[4];
#pragma unroll
  for (int r = 0; r < 4; r++) {
    float v = rsum[r];
    v += __shfl_xor(v, 1, 64);
    v += __shfl_xor(v, 2, 64);
    v += __shfl_xor(v, 4, 64);
    v += __shfl_xor(v, 8, 64);
    inv[r] = 1.f / v;
  }
  // attention out -> LDS Aa (swizzled [16][256], BKB=512)
#pragma unroll
  for (int fs = 0; fs < 2; fs++)
#pragma unroll
    for (int r = 0; r < 4; r++) {
      float val = accPV[fs][r] * inv[r] * dvo[fs];
      int row = lg * 4 + r, col = h * DH_ + fs * 16 + lr;
      int byte = (row * 512 + col * 2) ^ ((row & 7) << 4);
      *(unsigned short*)((char*)Aa + byte) = f2bf(val);
    }
  __syncthreads();   // Aa visible; all attention VMEM drained (vmcnt exact below)

  // ================= MLP: per-wave self-timed panel pipeline ====
  int lr16 = lr;
  f32x4 acc[2];
  acc[0] = (f32x4){0.f, 0.f, 0.f, 0.f};
  acc[1] = (f32x4){0.f, 0.f, 0.f, 0.f};
  const unsigned short* Asrc = Aa;

  // per-wave stage of OWN panel slice (rows w*32..w*32+31 = chunks w*4..w*4+3)
#define STAGE_OWN(PN, BUF)                                                        \
  {                                                                               \
    const unsigned short* gsrc = Wl + (size_t)((PN) >> 2) * 65536 + ((PN) & 3) * 64; \
    _Pragma("unroll")                                                             \
    for (int tt = 0; tt < 4; ++tt) {                                              \
      int c = w * 4 + tt;                                                         \
      int byteo = c * 1024 + lane * 16;                                           \
      int row = byteo >> 7;                                                       \
      int inner = (byteo & 127) ^ ((row & 7) << 4);                               \
      gload16(gsrc + (size_t)row * 256 + (inner >> 1), (BUF) + c * 512);          \
    }                                                                             \
  }

  STAGE_OWN(0, Bp[0])
  STAGE_OWN(1, Bp[1])

  for (int p = 0; p < 12; ++p) {
    if (p < 10) {
      int pn = p + 2;
      STAGE_OWN(pn, Bp[pn % 3])
      asm volatile("s_waitcnt vmcnt(8)" ::: "memory");   // own panel p ready
    } else if (p == 10) {
      asm volatile("s_waitcnt vmcnt(4)" ::: "memory");
    } else {
      asm volatile("s_waitcnt vmcnt(0)" ::: "memory");
    }
    __builtin_amdgcn_sched_barrier(0);

    int kk0 = (p & 3) * 64;
#pragma unroll
    for (int kk = 0; kk < 64; kk += 32) {
      bf16x8 a = lds_frag<512>(Asrc, lr16, (kk0 + kk) * 2 + lg * 16);
#pragma unroll
      for (int j = 0; j < 2; j++) {
        bf16x8 bfg = lds_frag<128>(Bp[p % 3], w * 32 + j * 16 + lr16, kk * 2 + lg * 16);
        acc[j] = __builtin_amdgcn_mfma_f32_16x16x32_bf16(a, bfg, acc[j], 0, 0, 0);
      }
    }
    if (p == 3 || p == 7) {
      const float* bvp = (p == 3) ? bv1 : bv2;
      unsigned short* dst = (p == 3) ? Ab : Ab2;
#pragma unroll
      for (int j = 0; j < 2; j++) {
        int col = w * 32 + j * 16 + lr16;
        float bv = bvp[j];
#pragma unroll
        for (int r = 0; r < 4; r++) {
          float v = acc[j][r] + bv;
          v = 0.5f * v * (1.f + erff(v * 0.70710678118654752f));
          int row = lg * 4 + r;
          int byte = (row * 512 + col * 2) ^ ((row & 7) << 4);
          *(unsigned short*)((char*)dst + byte) = f2bf(v);
        }
      }
      acc[0] = (f32x4){0.f, 0.f, 0.f, 0.f};
      acc[1] = (f32x4){0.f, 0.f, 0.f, 0.f};
      Asrc = (p == 3) ? Ab : Ab2;
      // cross-wave handoff: ds_writes visible, NO vmcnt drain (pipeline lives)
      asm volatile("s_waitcnt lgkmcnt(0)" ::: "memory");
      __builtin_amdgcn_sched_barrier(0);
      __builtin_amdgcn_s_barrier();
    }
  }

  // ---- final epilogue: bias3 + residual (+ next-layer LN dual emit) ----
#pragma unroll
  for (int j = 0; j < 2; j++) {
    int col = w * 32 + j * 16 + lr16;
    float bv = bv3[j];
#pragma unroll
    for (int r = 0; r < 4; r++) {
      int row = lg * 4 + r; int grow = r0 + row;
      float v = acc[j][r] + bv + x[(size_t)grow * D_ + col];
      if constexpr (LAST) {
        actB[(size_t)grow * D_ + col] = f2bf(v);
      } else {
        x[(size_t)grow * D_ + col] = v;
        xf[row][col] = v;
      }
    }
  }

  if constexpr (!LAST) {
    __syncthreads();
#pragma unroll
    for (int rr = 0; rr < 2; rr++) {
      int row = w * 2 + rr; int grow = r0 + row;
      f32x4 v = *(const f32x4*)&xf[row][lane * 4];
      float s = v[0] + v[1] + v[2] + v[3];
      float ss = v[0]*v[0] + v[1]*v[1] + v[2]*v[2] + v[3]*v[3];
#pragma unroll
      for (int off = 1; off < 64; off <<= 1) {
        s  += __shfl_xor(s, off, 64);
        ss += __shfl_xor(ss, off, 64);
      }
      float mean = s * (1.f / D_);
      float var = ss * (1.f / D_) - mean * mean;
      float rinv = rsqrtf(var + 1e-5f);
      float4 g4 = *(const float4*)(lngN + lane * 4);
      float4 b4 = *(const float4*)(lnbN + lane * 4);
      ushort4 o;
      o.x = f2bf((v[0] - mean) * rinv * g4.x + b4.x);
      o.y = f2bf((v[1] - mean) * rinv * g4.y + b4.y);
      o.z = f2bf((v[2] - mean) * rinv * g4.z + b4.z);
      o.w = f2bf((v[3] - mean) * rinv * g4.w + b4.w);
      *(ushort4*)(xbfN + (size_t)grow * D_ + lane * 4) = o;
      if (lane == 0) { mrow[row] = mean; rrow[row] = rinv; }
    }
    __syncthreads();
    int d = tid & 255, half = tid >> 8;
    float gd = lngN[d], bd = lnbN[d];
    int bb = r0 >> 10, s0 = r0 & 1023;
    bf16x8 o8;
#pragma unroll
    for (int k = 0; k < 8; k++) {
      int srow = half * 8 + k;
      o8[k] = (short)f2bf((xf[srow][d] - mrow[srow]) * rrow[srow] * gd + bd);
    }
    *(bf16x8*)(xnTN + ((size_t)(bb * 256 + d)) * S_ + s0 + half * 8) = o8;
  }
#undef STAGE_OWN
}

// ---------------- logits GEMM (round-23 best): Cs double-buffer, 1 barrier/iter ---
__global__ __launch_bounds__(512) void k_logits(
    const unsigned short* __restrict__ A,    // bf16 [4096][256]
    const float* __restrict__ logitW,        // f32 [256][32000]
    float* __restrict__ C) {
  __shared__ __align__(16) unsigned short Bs[128 * 256];    // 64 KB; reused as Cs[2]
  __shared__ __align__(16) unsigned short As[2][64 * 256];  // 2 x 32 KB

  int tid = threadIdx.x, lane = tid & 63, w = tid >> 6;
  int wm = w >> 2, wn = w & 3;               // 2 (row-groups) x 4 (col-groups)
  int lr = lane & 15, lg = lane >> 4;
  int bn0 = blockIdx.x * 128;

  // issue A tile 0 stage first (async; latency hides under the B-stage)
  stage_tile_swz<64, 256, 8>(A, 256, As[0], w, lane);

  // B-stage: transpose + convert logitW -> Bs [row=v][k] bf16, swizzled (BKB=512)
  {
    int c = tid & 127;          // col within slab (v - bn0)
    int kp = tid >> 7;          // 0..3
    for (int it = 0; it < 32; ++it) {
      int k = it * 8 + kp * 2;
      float f0 = logitW[(size_t)k * V_ + bn0 + c];
      float f1 = logitW[(size_t)(k + 1) * V_ + bn0 + c];
      unsigned pack = (unsigned)f2bf(f0) | ((unsigned)f2bf(f1) << 16);
      int byte = (c * 512 + k * 2) ^ ((c & 7) << 4);
      *(unsigned*)((char*)Bs + byte) = pack;
    }
  }
  __syncthreads();

  // hoist B fragments to registers
  bf16x8 breg[2][8];
#pragma unroll
  for (int j = 0; j < 2; j++)
#pragma unroll
    for (int ks = 0; ks < 8; ks++)
      breg[j][ks] = lds_frag<512>(Bs, wn * 32 + j * 16 + lr, ks * 64 + lg * 16);
  __syncthreads();   // all waves done reading Bs -> safe to reuse as Cs

  int crr = tid >> 5, ccc = tid & 31;        // repack-read coords

  for (int t = 0; t < 64; ++t) {
    int cur = t & 1;
    char* Cs = (char*)Bs + (t & 1) * 32768;  // double-buffered 32KB halves
    if (t < 63)
      stage_tile_swz<64, 256, 8>(A + (size_t)(t + 1) * 64 * 256, 256, As[cur ^ 1], w, lane);

    f32x4 acc[2][2];
#pragma unroll
    for (int i = 0; i < 2; i++)
#pragma unroll
      for (int j = 0; j < 2; j++) acc[i][j] = (f32x4){0.f, 0.f, 0.f, 0.f};

#pragma unroll
    for (int ks = 0; ks < 8; ks++) {
      bf16x8 af[2];
#pragma unroll
      for (int i = 0; i < 2; i++)
        af[i] = lds_frag<512>(As[cur], wm * 32 + i * 16 + lr, ks * 64 + lg * 16);
#pragma unroll
      for (int i = 0; i < 2; i++)
#pragma unroll
        for (int j = 0; j < 2; j++)
          acc[i][j] = __builtin_amdgcn_mfma_f32_16x16x32_bf16(breg[j][ks], af[i], acc[i][j], 0, 0, 0);
    }

    // acc -> Cs (swizzled)
#pragma unroll
    for (int i = 0; i < 2; i++)
#pragma unroll
      for (int j = 0; j < 2; j++) {
        int row = wm * 32 + i * 16 + lr;
        int byte = (row * 512 + (wn * 32 + j * 16 + lg * 4) * 4) ^ ((row & 7) << 4);
        *(f32x4*)(Cs + byte) = acc[i][j];
      }

    // single barrier: As(t+1) landed (vmcnt 4), Cs writes visible (lgkmcnt 0)
    asm volatile("s_waitcnt vmcnt(4) lgkmcnt(0)" ::: "memory");
    __builtin_amdgcn_sched_barrier(0);
    __builtin_amdgcn_s_barrier();

    // coalesced full-line nt stores: half-wave = one row's 512B
    int r0 = t * 64;
#pragma unroll
    for (int pss = 0; pss < 4; ++pss) {
      int row = pss * 16 + crr;
      int byte = (row * 512 + ccc * 16) ^ ((row & 7) << 4);
      f32x4 v = *(const f32x4*)(Cs + byte);
      __builtin_nontemporal_store(v, (f32x4*)(C + (size_t)(r0 + row) * V_ + bn0 + ccc * 4));
    }
  }
}

// ---------------- launch ----------------
extern "C" void kernel_launch(void* const* d_in, const int* in_sizes, int n_in,
                              void* d_out, int out_size, void* d_ws, size_t ws_size,
                              hipStream_t stream) {
  const int*   X      = (const int*)d_in[0];
  const float* emb    = (const float*)d_in[1];
  const float* WQ     = (const float*)d_in[2];
  const float* WK     = (const float*)d_in[3];
  const float* WV     = (const float*)d_in[4];
  const float* Om     = (const float*)d_in[5];
  const float* lng    = (const float*)d_in[6];
  const float* lnb    = (const float*)d_in[7];
  const float* w1     = (const float*)d_in[8];
  const float* b1     = (const float*)d_in[9];
  const float* w2     = (const float*)d_in[10];
  const float* b2     = (const float*)d_in[11];
  const float* w3     = (const float*)d_in[12];
  const float* b3     = (const float*)d_in[13];
  const float* logitW = (const float*)d_in[14];
  float* out = (float*)d_out;
  char* ws = (char*)d_ws;

  constexpr size_t MB = 1024u * 1024;
  float* x  = (float*)(ws);                                    // 4 MB
  unsigned short* xbf0 = (unsigned short*)(ws + 4 * MB);       // 2 MB
  unsigned short* xbf1 = (unsigned short*)(ws + 6 * MB);       // 2 MB
  unsigned short* xnT0 = (unsigned short*)(ws + 8 * MB);       // 2 MB
  unsigned short* xnT1 = (unsigned short*)(ws + 10 * MB);      // 2 MB
  unsigned short* actB = (unsigned short*)(ws + 12 * MB);      // 2 MB
  unsigned short* mlpW = (unsigned short*)(ws + 14 * MB);      // 1.5 MB

  // fused prep: embed+LN0 (256 blocks) + MLP weight tconv (192 blocks)
  k_prep<<<448, 512, 0, stream>>>(X, emb, lng, lnb, x, xbf0, xnT0, w1, w2, w3, mlpW);

  for (int l = 0; l < L_; l++) {
    const unsigned short* xbfI = (l & 1) ? xbf1 : xbf0;
    const unsigned short* xnTI = (l & 1) ? xnT1 : xnT0;
    unsigned short* xbfO = (l & 1) ? xbf0 : xbf1;
    unsigned short* xnTO = (l & 1) ? xnT0 : xnT1;
    if (l < L_ - 1) {
      k_layer<0><<<256, 512, 0, stream>>>(
          xbfI, xnTI, WQ, WK, WV, Om, mlpW + (size_t)(l * 3) * 65536,
          b1 + (size_t)l * D_, b2 + (size_t)l * D_, b3 + (size_t)l * D_, x,
          lng + (size_t)(l + 1) * D_, lnb + (size_t)(l + 1) * D_,
          xbfO, xnTO, nullptr, l);
    } else {
      k_layer<1><<<256, 512, 0, stream>>>(
          xbfI, xnTI, WQ, WK, WV, Om, mlpW + (size_t)(l * 3) * 65536,
          b1 + (size_t)l * D_, b2 + (size_t)l * D_, b3 + (size_t)l * D_, x,
          nullptr, nullptr, nullptr, nullptr, actB, l);
    }
  }

  // logits: Cs double-buffer repack, one barrier/iter
  k_logits<<<250, 512, 0, stream>>>(actB, logitW, out);
}

// Round 25
// 287.188 us; speedup vs baseline: 1.5060x; 1.0123x over previous
//
#include <hip/hip_runtime.h>
#include <hip/hip_bf16.h>
#include <cstdint>
#include <cstddef>

#define B_ 4
#define S_ 1024
#define V_ 32000
#define D_ 256
#define H_ 8
#define DH_ 32
#define L_ 4
#define MROWS (B_*S_)

typedef __attribute__((ext_vector_type(8))) short bf16x8;
typedef __attribute__((ext_vector_type(4))) float f32x4;

__device__ __forceinline__ unsigned short f2bf(float f) {
  union { float f; unsigned u; } c; c.f = f;
  unsigned u = c.u;
  u += 0x7fff + ((u >> 16) & 1);   // round-to-nearest-even
  return (unsigned short)(u >> 16);
}
__device__ __forceinline__ float bf2f(unsigned short u) {
  union { unsigned u; float f; } c; c.u = ((unsigned)u) << 16; return c.f;
}

// async global->LDS, 16B per lane; LDS dest is wave-uniform base + lane*16
__device__ __forceinline__ void gload16(const unsigned short* g, unsigned short* l) {
  __builtin_amdgcn_global_load_lds(
      (const __attribute__((address_space(1))) void*)g,
      (__attribute__((address_space(3))) void*)l, 16, 0, 0);
}

// ---- XOR-swizzled LDS tiles: lds[row][inner ^ ((row&7)<<4)] = g[row][inner]
template<int BM, int BK, int NW>
__device__ __forceinline__ void stage_tile_swz(const unsigned short* __restrict__ g, int ldg,
                                               unsigned short* lds, int wave, int lane) {
  constexpr int CH  = BM * BK * 2 / 1024;   // 1KB chunks
  constexpr int BKB = BK * 2;               // bytes per row
#pragma unroll
  for (int t = 0; t < CH / NW; ++t) {
    int c = wave + t * NW;
    int byte  = c * 1024 + lane * 16;
    int row   = byte / BKB;
    int inner = (byte % BKB) ^ ((row & 7) << 4);
    gload16(g + (size_t)row * ldg + (inner >> 1), lds + c * 512);
  }
}

// swizzled 16B fragment read: row-major [*][BKB/2] tile, kbytes multiple of 16
template<int BKB>
__device__ __forceinline__ bf16x8 lds_frag(const unsigned short* base, int row, int kbytes) {
  int b = (row * BKB + kbytes) ^ ((row & 7) << 4);
  return *(const bf16x8*)((const char*)base + b);
}

// ---------------- fused prep: embln (blocks 0..255) + MLP W tconv (256..447) ------
__global__ __launch_bounds__(512) void k_prep(
    const int* __restrict__ X, const float* __restrict__ emb,
    const float* __restrict__ lng, const float* __restrict__ lnb,
    float* __restrict__ x, unsigned short* __restrict__ xbf,
    unsigned short* __restrict__ xnT,
    const float* __restrict__ w1, const float* __restrict__ w2,
    const float* __restrict__ w3, unsigned short* __restrict__ mlpW) {
  int tid = threadIdx.x;
  if (blockIdx.x < 256) {
    __shared__ __align__(16) float xf[16][264];
    __shared__ float mrow[16], rrow[16];
    int r0 = blockIdx.x * 16;
    int w = tid >> 6, lane = tid & 63;
#pragma unroll
    for (int rr = 0; rr < 2; rr++) {
      int row = w * 2 + rr; int grow = r0 + row;
      int tok = X[grow];
      f32x4 v = *(const f32x4*)(emb + (size_t)tok * D_ + lane * 4);
      *(f32x4*)(x + (size_t)grow * D_ + lane * 4) = v;
      *(f32x4*)&xf[row][lane * 4] = v;
      float s = v[0] + v[1] + v[2] + v[3];
      float ss = v[0]*v[0] + v[1]*v[1] + v[2]*v[2] + v[3]*v[3];
#pragma unroll
      for (int off = 1; off < 64; off <<= 1) {
        s  += __shfl_xor(s, off, 64);
        ss += __shfl_xor(ss, off, 64);
      }
      float mean = s * (1.f / D_);
      float var = ss * (1.f / D_) - mean * mean;
      float rinv = rsqrtf(var + 1e-5f);
      float4 g4 = *(const float4*)(lng + lane * 4);
      float4 b4 = *(const float4*)(lnb + lane * 4);
      ushort4 o;
      o.x = f2bf((v[0] - mean) * rinv * g4.x + b4.x);
      o.y = f2bf((v[1] - mean) * rinv * g4.y + b4.y);
      o.z = f2bf((v[2] - mean) * rinv * g4.z + b4.z);
      o.w = f2bf((v[3] - mean) * rinv * g4.w + b4.w);
      *(ushort4*)(xbf + (size_t)grow * D_ + lane * 4) = o;
      if (lane == 0) { mrow[row] = mean; rrow[row] = rinv; }
    }
    __syncthreads();
    int d = tid & 255, half = tid >> 8;
    float gd = lng[d], bd = lnb[d];
    int bb = r0 >> 10, s0 = r0 & 1023;
    bf16x8 o8;
#pragma unroll
    for (int k = 0; k < 8; k++) {
      int srow = half * 8 + k;
      o8[k] = (short)f2bf((xf[srow][d] - mrow[srow]) * rrow[srow] * gd + bd);
    }
    *(bf16x8*)(xnT + ((size_t)(bb * 256 + d)) * S_ + s0 + half * 8) = o8;
  } else {
    __shared__ float tile[64][65];
    int idx = blockIdx.x - 256;               // 0..191
    int z = idx >> 4;                         // 0..11  (l*3+mm)
    int rem = idx & 15;
    int r0 = (rem >> 2) * 64, c0 = (rem & 3) * 64;
    int l = z / 3, mm = z % 3;
    const float* in = (mm == 0 ? w1 : mm == 1 ? w2 : w3) + (size_t)l * 65536;
    unsigned short* out = mlpW + (size_t)z * 65536;
    int t = tid & 255;
    bool act = tid < 256;
    if (act) {
#pragma unroll
      for (int i = 0; i < 16; i++) {
        int id2 = i * 256 + t;
        int lr = id2 >> 6, lc = id2 & 63;
        tile[lr][lc] = in[(size_t)(r0 + lr) * 256 + c0 + lc];
      }
    }
    __syncthreads();
    if (act) {
#pragma unroll
      for (int i = 0; i < 16; i++) {
        int id2 = i * 256 + t;
        int lr = id2 >> 6, lc = id2 & 63;
        out[(size_t)(c0 + lr) * 256 + r0 + lc] = f2bf(tile[lc][lr]);
      }
    }
  }
}

// ---------------- fused layer (round-24 best): per-wave self-timed MLP ------------
template<int LAST>
__global__ __launch_bounds__(512) void k_layer(
    const unsigned short* __restrict__ xbf,   // layer input  [4096][256] bf16
    const unsigned short* __restrict__ xnT,   // layer input  [4][256][1024] bf16
    const float* __restrict__ WQ, const float* __restrict__ WK,
    const float* __restrict__ WV, const float* __restrict__ Om,
    const unsigned short* __restrict__ Wl,    // 3 x [256][256] bf16 (this layer)
    const float* __restrict__ b1, const float* __restrict__ b2, const float* __restrict__ b3,
    float* __restrict__ x,                    // residual f32
    const float* __restrict__ lngN, const float* __restrict__ lnbN,
    unsigned short* __restrict__ xbfN, unsigned short* __restrict__ xnTN,  // outputs (!LAST)
    unsigned short* __restrict__ actB,        // output (LAST)
    int layer) {
  __shared__ __align__(16) unsigned short P_lds[8][16][72];
  __shared__ __align__(16) unsigned short Aa[16 * 256];
  __shared__ __align__(16) unsigned short Ab[16 * 256];
  __shared__ __align__(16) unsigned short Ab2[16 * 256];
  __shared__ __align__(16) unsigned short Bp[3][256 * 64];
  __shared__ __align__(16) float xf[16][264];
  __shared__ float mrow[16], rrow[16];

  int b = blockIdx.x >> 6;
  int q0 = (blockIdx.x & 63) << 4;
  int r0 = blockIdx.x * 16;                  // == b*S + q0
  int tid = threadIdx.x;
  int w = tid >> 6, lane = tid & 63;
  int lr = lane & 15, lg = lane >> 4;
  int h = w;

  // ================= attention =================
  const float scale = 0.17677669529663687f;  // 1/sqrt(32)
  bf16x8 aq;
  {
    bf16x8 xq = *(const bf16x8*)(xbf + ((size_t)(b * S_ + q0 + lr)) * D_ + h * DH_ + lg * 8);
#pragma unroll
    for (int j = 0; j < 8; j++) {
      int dj = lg * 8 + j;
      float wq = WQ[((size_t)(layer * H_ + h)) * 1024 + dj * 33];
      float wk = WK[((size_t)(layer * H_ + h)) * 1024 + dj * 33];
      aq[j] = (short)f2bf(bf2f((unsigned short)xq[j]) * wq * wk * scale);
    }
  }
  float dvo[2];
#pragma unroll
  for (int fs = 0; fs < 2; fs++) {
    int fh = fs * 16 + lr;
    int fc = h * DH_ + fh;
    dvo[fs] = WV[((size_t)(layer * H_ + h)) * 1024 + fh * 33] *
              Om[(size_t)layer * 65536 + (size_t)fc * 257];
  }
  // hoist MLP biases to registers (keeps the panel loop free of VMEM ops)
  float bv1[2], bv2[2], bv3[2];
#pragma unroll
  for (int j = 0; j < 2; j++) {
    int col = w * 32 + j * 16 + lr;
    bv1[j] = b1[col]; bv2[j] = b2[col]; bv3[j] = b3[col];
  }

  f32x4 accPV[2];
  accPV[0] = (f32x4){0.f, 0.f, 0.f, 0.f};
  accPV[1] = (f32x4){0.f, 0.f, 0.f, 0.f};
  float rsum[4] = {0.f, 0.f, 0.f, 0.f};

  const unsigned short* xk_base = xbf + ((size_t)b * S_) * D_ + h * DH_ + lg * 8;
  const unsigned short* vT_base = xnT + ((size_t)(b * D_ + h * DH_)) * S_;

  bf16x8 qkb[4];
#pragma unroll
  for (int c = 0; c < 4; c++)
    qkb[c] = *(const bf16x8*)(xk_base + (size_t)(c * 16 + lr) * D_);

  for (int kt = 0; kt < 16; kt++) {
    int k0 = kt * 64;
    bf16x8 pvb[2][2];
#pragma unroll
    for (int fs = 0; fs < 2; fs++)
#pragma unroll
      for (int kc = 0; kc < 2; kc++)
        pvb[fs][kc] = *(const bf16x8*)(vT_base + (size_t)(fs * 16 + lr) * S_ +
                                       k0 + kc * 32 + lg * 8);
    f32x4 s[4];
#pragma unroll
    for (int c = 0; c < 4; c++)
      s[c] = __builtin_amdgcn_mfma_f32_16x16x32_bf16(aq, qkb[c],
                (f32x4){0.f, 0.f, 0.f, 0.f}, 0, 0, 0);
    int ktn = kt < 15 ? kt + 1 : 15;
#pragma unroll
    for (int c = 0; c < 4; c++)
      qkb[c] = *(const bf16x8*)(xk_base + (size_t)(ktn * 64 + c * 16 + lr) * D_);
#pragma unroll
    for (int c = 0; c < 4; c++)
#pragma unroll
      for (int r = 0; r < 4; r++) {
        float p = __expf(s[c][r]);
        rsum[r] += p;
        P_lds[w][lg * 4 + r][c * 16 + lr] = f2bf(p);
      }
#pragma unroll
    for (int kc = 0; kc < 2; kc++) {
      bf16x8 pa = *(const bf16x8*)(&P_lds[w][lr][kc * 32 + lg * 8]);
#pragma unroll
      for (int fs = 0; fs < 2; fs++)
        accPV[fs] = __builtin_amdgcn_mfma_f32_16x16x32_bf16(pa, pvb[fs][kc],
                       accPV[fs], 0, 0, 0);
    }
  }

  float inv[4];
#pragma unroll
  for (int r = 0; r < 4; r++) {
    float v = rsum[r];
    v += __shfl_xor(v, 1, 64);
    v += __shfl_xor(v, 2, 64);
    v += __shfl_xor(v, 4, 64);
    v += __shfl_xor(v, 8, 64);
    inv[r] = 1.f / v;
  }
  // attention out -> LDS Aa (swizzled [16][256], BKB=512)
#pragma unroll
  for (int fs = 0; fs < 2; fs++)
#pragma unroll
    for (int r = 0; r < 4; r++) {
      float val = accPV[fs][r] * inv[r] * dvo[fs];
      int row = lg * 4 + r, col = h * DH_ + fs * 16 + lr;
      int byte = (row * 512 + col * 2) ^ ((row & 7) << 4);
      *(unsigned short*)((char*)Aa + byte) = f2bf(val);
    }
  __syncthreads();   // Aa visible

  // ================= MLP: per-wave self-timed panel pipeline ====
  int lr16 = lr;
  f32x4 acc[2];
  acc[0] = (f32x4){0.f, 0.f, 0.f, 0.f};
  acc[1] = (f32x4){0.f, 0.f, 0.f, 0.f};
  const unsigned short* Asrc = Aa;

#define STAGE_OWN(PN, BUF)                                                        \
  {                                                                               \
    const unsigned short* gsrc = Wl + (size_t)((PN) >> 2) * 65536 + ((PN) & 3) * 64; \
    _Pragma("unroll")                                                             \
    for (int tt = 0; tt < 4; ++tt) {                                              \
      int c = w * 4 + tt;                                                         \
      int byteo = c * 1024 + lane * 16;                                           \
      int row = byteo >> 7;                                                       \
      int inner = (byteo & 127) ^ ((row & 7) << 4);                               \
      gload16(gsrc + (size_t)row * 256 + (inner >> 1), (BUF) + c * 512);          \
    }                                                                             \
  }

  STAGE_OWN(0, Bp[0])
  STAGE_OWN(1, Bp[1])

  for (int p = 0; p < 12; ++p) {
    if (p < 10) {
      int pn = p + 2;
      STAGE_OWN(pn, Bp[pn % 3])
      asm volatile("s_waitcnt vmcnt(8)" ::: "memory");   // own panel p ready
    } else if (p == 10) {
      asm volatile("s_waitcnt vmcnt(4)" ::: "memory");
    } else {
      asm volatile("s_waitcnt vmcnt(0)" ::: "memory");
    }
    __builtin_amdgcn_sched_barrier(0);

    int kk0 = (p & 3) * 64;
#pragma unroll
    for (int kk = 0; kk < 64; kk += 32) {
      bf16x8 a = lds_frag<512>(Asrc, lr16, (kk0 + kk) * 2 + lg * 16);
#pragma unroll
      for (int j = 0; j < 2; j++) {
        bf16x8 bfg = lds_frag<128>(Bp[p % 3], w * 32 + j * 16 + lr16, kk * 2 + lg * 16);
        acc[j] = __builtin_amdgcn_mfma_f32_16x16x32_bf16(a, bfg, acc[j], 0, 0, 0);
      }
    }
    if (p == 3 || p == 7) {
      const float* bvp = (p == 3) ? bv1 : bv2;
      unsigned short* dst = (p == 3) ? Ab : Ab2;
#pragma unroll
      for (int j = 0; j < 2; j++) {
        int col = w * 32 + j * 16 + lr16;
        float bv = bvp[j];
#pragma unroll
        for (int r = 0; r < 4; r++) {
          float v = acc[j][r] + bv;
          v = 0.5f * v * (1.f + erff(v * 0.70710678118654752f));
          int row = lg * 4 + r;
          int byte = (row * 512 + col * 2) ^ ((row & 7) << 4);
          *(unsigned short*)((char*)dst + byte) = f2bf(v);
        }
      }
      acc[0] = (f32x4){0.f, 0.f, 0.f, 0.f};
      acc[1] = (f32x4){0.f, 0.f, 0.f, 0.f};
      Asrc = (p == 3) ? Ab : Ab2;
      asm volatile("s_waitcnt lgkmcnt(0)" ::: "memory");
      __builtin_amdgcn_sched_barrier(0);
      __builtin_amdgcn_s_barrier();
    }
  }

  // ---- final epilogue: bias3 + residual (+ next-layer LN dual emit) ----
#pragma unroll
  for (int j = 0; j < 2; j++) {
    int col = w * 32 + j * 16 + lr16;
    float bv = bv3[j];
#pragma unroll
    for (int r = 0; r < 4; r++) {
      int row = lg * 4 + r; int grow = r0 + row;
      float v = acc[j][r] + bv + x[(size_t)grow * D_ + col];
      if constexpr (LAST) {
        actB[(size_t)grow * D_ + col] = f2bf(v);
      } else {
        x[(size_t)grow * D_ + col] = v;
        xf[row][col] = v;
      }
    }
  }

  if constexpr (!LAST) {
    __syncthreads();
#pragma unroll
    for (int rr = 0; rr < 2; rr++) {
      int row = w * 2 + rr; int grow = r0 + row;
      f32x4 v = *(const f32x4*)&xf[row][lane * 4];
      float s = v[0] + v[1] + v[2] + v[3];
      float ss = v[0]*v[0] + v[1]*v[1] + v[2]*v[2] + v[3]*v[3];
#pragma unroll
      for (int off = 1; off < 64; off <<= 1) {
        s  += __shfl_xor(s, off, 64);
        ss += __shfl_xor(ss, off, 64);
      }
      float mean = s * (1.f / D_);
      float var = ss * (1.f / D_) - mean * mean;
      float rinv = rsqrtf(var + 1e-5f);
      float4 g4 = *(const float4*)(lngN + lane * 4);
      float4 b4 = *(const float4*)(lnbN + lane * 4);
      ushort4 o;
      o.x = f2bf((v[0] - mean) * rinv * g4.x + b4.x);
      o.y = f2bf((v[1] - mean) * rinv * g4.y + b4.y);
      o.z = f2bf((v[2] - mean) * rinv * g4.z + b4.z);
      o.w = f2bf((v[3] - mean) * rinv * g4.w + b4.w);
      *(ushort4*)(xbfN + (size_t)grow * D_ + lane * 4) = o;
      if (lane == 0) { mrow[row] = mean; rrow[row] = rinv; }
    }
    __syncthreads();
    int d = tid & 255, half = tid >> 8;
    float gd = lngN[d], bd = lnbN[d];
    int bb = r0 >> 10, s0 = r0 & 1023;
    bf16x8 o8;
#pragma unroll
    for (int k = 0; k < 8; k++) {
      int srow = half * 8 + k;
      o8[k] = (short)f2bf((xf[srow][d] - mrow[srow]) * rrow[srow] * gd + bd);
    }
    *(bf16x8*)(xnTN + ((size_t)(bb * 256 + d)) * S_ + s0 + half * 8) = o8;
  }
#undef STAGE_OWN
}

// ---------------- logits GEMM v8: 500 blocks (2/CU), 64-col slabs, repack ---------
// r23 structure shrunk to 64KB LDS (Bs 32K + As 2x16K; Cs[2] 2x8K inside dead Bs)
// -> 2 blocks/CU so one block's compute overlaps the other's store-drain wait.
// Same per-element k-order -> bit-identical output.
__global__ __launch_bounds__(512) void k_logits(
    const unsigned short* __restrict__ A,    // bf16 [4096][256]
    const float* __restrict__ logitW,        // f32 [256][32000]
    float* __restrict__ C) {
  __shared__ __align__(16) unsigned short Bs[64 * 256];     // 32 KB; reused as Cs[2]
  __shared__ __align__(16) unsigned short As[2][32 * 256];  // 2 x 16 KB

  int tid = threadIdx.x, lane = tid & 63, w = tid >> 6;
  int wm = w >> 2, wn = w & 3;               // 2 (row-groups of 16) x 4 (col-groups of 16)
  int lr = lane & 15, lg = lane >> 4;
  int bn0 = blockIdx.x * 64;

  // issue A tile 0 stage first (async; latency hides under the B-stage)
  stage_tile_swz<32, 256, 8>(A, 256, As[0], w, lane);

  // B-stage: transpose + convert logitW -> Bs [row=v][k] bf16, swizzled (BKB=512)
  {
    int c = tid & 63;           // col within slab (v - bn0)
    int kp = tid >> 6;          // 0..7
    for (int it = 0; it < 16; ++it) {
      int k = it * 16 + kp * 2;
      float f0 = logitW[(size_t)k * V_ + bn0 + c];
      float f1 = logitW[(size_t)(k + 1) * V_ + bn0 + c];
      unsigned pack = (unsigned)f2bf(f0) | ((unsigned)f2bf(f1) << 16);
      int byte = (c * 512 + k * 2) ^ ((c & 7) << 4);
      *(unsigned*)((char*)Bs + byte) = pack;
    }
  }
  __syncthreads();

  // hoist B fragments to registers (wave covers cols wn*16..+15)
  bf16x8 breg[8];
#pragma unroll
  for (int ks = 0; ks < 8; ks++)
    breg[ks] = lds_frag<512>(Bs, wn * 16 + lr, ks * 64 + lg * 16);
  __syncthreads();   // all waves done reading Bs -> safe to reuse as Cs

  int crr = tid >> 4, ccc = tid & 15;        // repack-read: row 0..31, 16B-chunk 0..15

  for (int t = 0; t < 128; ++t) {
    int cur = t & 1;
    char* Cs = (char*)Bs + (t & 1) * 8192;   // double-buffered 8KB halves
    if (t < 127)
      stage_tile_swz<32, 256, 8>(A + (size_t)(t + 1) * 32 * 256, 256, As[cur ^ 1], w, lane);

    f32x4 acc = (f32x4){0.f, 0.f, 0.f, 0.f};
#pragma unroll
    for (int ks = 0; ks < 8; ks++) {
      bf16x8 af = lds_frag<512>(As[cur], wm * 16 + lr, ks * 64 + lg * 16);
      // swapped operands: lane = A-row (lr), regs = 4 vocab cols
      acc = __builtin_amdgcn_mfma_f32_16x16x32_bf16(breg[ks], af, acc, 0, 0, 0);
    }

    // acc -> Cs (swizzled [32 rows][256B])
    {
      int row = wm * 16 + lr;
      int byte = (row * 256 + (wn * 16 + lg * 4) * 4) ^ ((row & 7) << 4);
      *(f32x4*)(Cs + byte) = acc;
    }

    // single barrier: As(t+1) landed (vmcnt 2: 2 loads oldest after 1 store),
    // Cs writes visible (lgkmcnt 0)
    asm volatile("s_waitcnt vmcnt(2) lgkmcnt(0)" ::: "memory");
    __builtin_amdgcn_sched_barrier(0);
    __builtin_amdgcn_s_barrier();

    // coalesced full-line nt stores: 16 lanes = one row's 256B (2 full lines)
    int r0 = t * 32;
    {
      int byte = (crr * 256 + ccc * 16) ^ ((crr & 7) << 4);
      f32x4 v = *(const f32x4*)(Cs + byte);
      __builtin_nontemporal_store(v, (f32x4*)(C + (size_t)(r0 + crr) * V_ + bn0 + ccc * 4));
    }
  }
}

// ---------------- launch ----------------
extern "C" void kernel_launch(void* const* d_in, const int* in_sizes, int n_in,
                              void* d_out, int out_size, void* d_ws, size_t ws_size,
                              hipStream_t stream) {
  const int*   X      = (const int*)d_in[0];
  const float* emb    = (const float*)d_in[1];
  const float* WQ     = (const float*)d_in[2];
  const float* WK     = (const float*)d_in[3];
  const float* WV     = (const float*)d_in[4];
  const float* Om     = (const float*)d_in[5];
  const float* lng    = (const float*)d_in[6];
  const float* lnb    = (const float*)d_in[7];
  const float* w1     = (const float*)d_in[8];
  const float* b1     = (const float*)d_in[9];
  const float* w2     = (const float*)d_in[10];
  const float* b2     = (const float*)d_in[11];
  const float* w3     = (const float*)d_in[12];
  const float* b3     = (const float*)d_in[13];
  const float* logitW = (const float*)d_in[14];
  float* out = (float*)d_out;
  char* ws = (char*)d_ws;

  constexpr size_t MB = 1024u * 1024;
  float* x  = (float*)(ws);                                    // 4 MB
  unsigned short* xbf0 = (unsigned short*)(ws + 4 * MB);       // 2 MB
  unsigned short* xbf1 = (unsigned short*)(ws + 6 * MB);       // 2 MB
  unsigned short* xnT0 = (unsigned short*)(ws + 8 * MB);       // 2 MB
  unsigned short* xnT1 = (unsigned short*)(ws + 10 * MB);      // 2 MB
  unsigned short* actB = (unsigned short*)(ws + 12 * MB);      // 2 MB
  unsigned short* mlpW = (unsigned short*)(ws + 14 * MB);      // 1.5 MB

  // fused prep: embed+LN0 (256 blocks) + MLP weight tconv (192 blocks)
  k_prep<<<448, 512, 0, stream>>>(X, emb, lng, lnb, x, xbf0, xnT0, w1, w2, w3, mlpW);

  for (int l = 0; l < L_; l++) {
    const unsigned short* xbfI = (l & 1) ? xbf1 : xbf0;
    const unsigned short* xnTI = (l & 1) ? xnT1 : xnT0;
    unsigned short* xbfO = (l & 1) ? xbf0 : xbf1;
    unsigned short* xnTO = (l & 1) ? xnT0 : xnT1;
    if (l < L_ - 1) {
      k_layer<0><<<256, 512, 0, stream>>>(
          xbfI, xnTI, WQ, WK, WV, Om, mlpW + (size_t)(l * 3) * 65536,
          b1 + (size_t)l * D_, b2 + (size_t)l * D_, b3 + (size_t)l * D_, x,
          lng + (size_t)(l + 1) * D_, lnb + (size_t)(l + 1) * D_,
          xbfO, xnTO, nullptr, l);
    } else {
      k_layer<1><<<256, 512, 0, stream>>>(
          xbfI, xnTI, WQ, WK, WV, Om, mlpW + (size_t)(l * 3) * 65536,
          b1 + (size_t)l * D_, b2 + (size_t)l * D_, b3 + (size_t)l * D_, x,
          nullptr, nullptr, nullptr, nullptr, actB, l);
    }
  }

  // logits: 500 blocks (2/CU), 64-col slabs, Cs double-buffer repack
  k_logits<<<500, 512, 0, stream>>>(actB, logitW, out);
}